// Round 1
// baseline (4134.804 us; speedup 1.0000x reference)
//
#include <hip/hip_runtime.h>
#include <math.h>

#define NN 25000
#define NE 50000
#define NATOM 26
#define HID 64
#define NG 64
#define NUM_ITER 3
#define U_STRIDE 132   // 128 relu feats + 1.0 slot (be2 fold) + 3 zero pad
#define EB 64          // edges per block in edge_msg
#define NPB 32         // nodes per block in node_update

// ---------------- K1: per-edge MLP layer 1: U = [relu(ea@We1+be1), 1, 0,0,0]
__global__ __launch_bounds__(128) void edge_mlp_kernel(
    const float* __restrict__ ea, const float* __restrict__ We1,
    const float* __restrict__ be1, float* __restrict__ U) {
  int e = blockIdx.x;
  int t = threadIdx.x;  // 0..127
  float a0 = ea[e * 4 + 0], a1 = ea[e * 4 + 1], a2 = ea[e * 4 + 2], a3 = ea[e * 4 + 3];
  float v = be1[t];
  v = fmaf(a0, We1[t], v);
  v = fmaf(a1, We1[128 + t], v);
  v = fmaf(a2, We1[256 + t], v);
  v = fmaf(a3, We1[384 + t], v);
  U[(size_t)e * U_STRIDE + t] = fmaxf(v, 0.f);
  if (t == 0) {
    U[(size_t)e * U_STRIDE + 128] = 1.f;  // multiplies the be2 row
    U[(size_t)e * U_STRIDE + 129] = 0.f;
    U[(size_t)e * U_STRIDE + 130] = 0.f;
    U[(size_t)e * U_STRIDE + 131] = 0.f;
  }
}

// ---------------- K2: input node transform: h = relu(x@W_in + b_in)   (out==h invariant)
__global__ __launch_bounds__(256) void node_in_kernel(
    const float* __restrict__ x, const float* __restrict__ W_in,
    const float* __restrict__ b_in, float* __restrict__ h) {
  int idx = blockIdx.x * 256 + threadIdx.x;
  if (idx >= NN * HID) return;
  int n = idx >> 6, c = idx & 63;
  float acc = b_in[c];
  #pragma unroll
  for (int j = 0; j < NATOM; ++j) acc = fmaf(x[n * NATOM + j], W_in[j * HID + c], acc);
  h[idx] = fmaxf(acc, 0.f);
}

// ---------------- K4: fused edge message + scatter-add
// msg[e][o] = sum_k U[e][k] * (sum_i s[e][i] * W2row[k][i*64+o]),  W2row[128]=be2
__global__ __launch_bounds__(256) void edge_msg_kernel(
    const float* __restrict__ U, const float* __restrict__ hv,
    const int* __restrict__ src, const int* __restrict__ dst,
    const float* __restrict__ We2, const float* __restrict__ be2,
    float* __restrict__ agg) {
  __shared__ float s_tile[EB * HID];     // 16 KB : s[e][i] = h[src[e]][i]
  __shared__ float w_chunk[4 * 4096];    // 64 KB : 4 rows of We2 (k-chunk)
  int tid = threadIdx.x;
  int e0 = blockIdx.x * EB;

  for (int idx = tid; idx < EB * HID; idx += 256) {
    int eg = e0 + (idx >> 6);
    s_tile[idx] = (eg < NE) ? hv[(size_t)src[eg] * HID + (idx & 63)] : 0.f;
  }
  int o = tid & 63, g = tid >> 6;
  float acc[16];
  #pragma unroll
  for (int j = 0; j < 16; ++j) acc[j] = 0.f;
  __syncthreads();

  for (int kc = 0; kc < U_STRIDE; kc += 4) {
    // stage 4 k-rows of the (extended) We2 into LDS, float4-vectorized
    for (int idx = tid; idx < 4 * 1024; idx += 256) {
      int kk = idx >> 10, c4 = idx & 1023;
      int k = kc + kk;
      float4 wv;
      if (k < 128)       wv = ((const float4*)We2)[(size_t)k * 1024 + c4];
      else if (k == 128) wv = ((const float4*)be2)[c4];
      else               wv = make_float4(0.f, 0.f, 0.f, 0.f);
      ((float4*)w_chunk)[idx] = wv;
    }
    __syncthreads();

    float pacc[16][4];
    #pragma unroll
    for (int j = 0; j < 16; ++j) {
      #pragma unroll
      for (int kk = 0; kk < 4; ++kk) pacc[j][kk] = 0.f;
    }
    #pragma unroll 2
    for (int i = 0; i < 64; ++i) {
      float w0 = w_chunk[          i * 64 + o];
      float w1 = w_chunk[ 4096 +   i * 64 + o];
      float w2 = w_chunk[ 8192 +   i * 64 + o];
      float w3 = w_chunk[12288 +   i * 64 + o];
      #pragma unroll
      for (int j = 0; j < 16; ++j) {
        float sv = s_tile[(g + 4 * j) * 64 + i];  // wave-broadcast
        pacc[j][0] = fmaf(sv, w0, pacc[j][0]);
        pacc[j][1] = fmaf(sv, w1, pacc[j][1]);
        pacc[j][2] = fmaf(sv, w2, pacc[j][2]);
        pacc[j][3] = fmaf(sv, w3, pacc[j][3]);
      }
    }
    #pragma unroll
    for (int j = 0; j < 16; ++j) {
      int eg = e0 + g + 4 * j;
      if (eg < NE) {
        const float* up = U + (size_t)eg * U_STRIDE + kc;
        acc[j] = fmaf(up[0], pacc[j][0], acc[j]);
        acc[j] = fmaf(up[1], pacc[j][1], acc[j]);
        acc[j] = fmaf(up[2], pacc[j][2], acc[j]);
        acc[j] = fmaf(up[3], pacc[j][3], acc[j]);
      }
    }
    __syncthreads();
  }
  #pragma unroll
  for (int j = 0; j < 16; ++j) {
    int eg = e0 + g + 4 * j;
    if (eg < NE) atomicAdd(&agg[(size_t)dst[eg] * HID + o], acc[j]);
  }
}

// ---------------- K5: m = relu(h@W_root + agg + b_conv); GRU(h, m) -> h  (in place)
__global__ __launch_bounds__(256) void node_update_kernel(
    float* __restrict__ hv, const float* __restrict__ agg,
    const float* __restrict__ W_root, const float* __restrict__ b_conv,
    const float* __restrict__ W_ih, const float* __restrict__ b_ih,
    const float* __restrict__ W_hh, const float* __restrict__ b_hh) {
  __shared__ float wroot[64 * 64];      // [i][c]
  __shared__ float wihT[64 * 193];      // [i][j] padded stride 193 -> conflict-free
  __shared__ float whhT[64 * 193];
  __shared__ float s_row[NPB * 64];     // h rows (== out rows)
  __shared__ float s_m[NPB * 64];
  int tid = threadIdx.x;
  int n0 = blockIdx.x * NPB;

  for (int idx = tid; idx < 64 * 16; idx += 256)  // wroot via float4
    ((float4*)wroot)[idx] = ((const float4*)W_root)[idx];
  for (int idx4 = tid; idx4 < 192 * 16; idx4 += 256) {
    int j = idx4 >> 4, i4 = (idx4 & 15) * 4;
    float4 a = ((const float4*)W_ih)[idx4];
    float4 b = ((const float4*)W_hh)[idx4];
    wihT[(i4 + 0) * 193 + j] = a.x; wihT[(i4 + 1) * 193 + j] = a.y;
    wihT[(i4 + 2) * 193 + j] = a.z; wihT[(i4 + 3) * 193 + j] = a.w;
    whhT[(i4 + 0) * 193 + j] = b.x; whhT[(i4 + 1) * 193 + j] = b.y;
    whhT[(i4 + 2) * 193 + j] = b.z; whhT[(i4 + 3) * 193 + j] = b.w;
  }
  for (int idx = tid; idx < NPB * 64; idx += 256) {
    int n = n0 + (idx >> 6);
    s_row[idx] = (n < NN) ? hv[(size_t)n * 64 + (idx & 63)] : 0.f;
  }
  __syncthreads();

  int c = tid & 63, g = tid >> 6;
  // phase 1: m
  #pragma unroll
  for (int q = 0; q < 8; ++q) {
    int nl = g + 4 * q;
    int n = n0 + nl;
    float a = 0.f;
    for (int i = 0; i < 64; ++i) a = fmaf(s_row[nl * 64 + i], wroot[i * 64 + c], a);
    float val = 0.f;
    if (n < NN) val = fmaxf(a + agg[(size_t)n * 64 + c] + b_conv[c], 0.f);
    s_m[nl * 64 + c] = val;
  }
  __syncthreads();
  // phase 2+3: GRU
  #pragma unroll
  for (int q = 0; q < 8; ++q) {
    int nl = g + 4 * q;
    int n = n0 + nl;
    if (n >= NN) continue;
    float gir = b_ih[c], giz = b_ih[64 + c], gin = b_ih[128 + c];
    float ghr = b_hh[c], ghz = b_hh[64 + c], ghn = b_hh[128 + c];
    for (int i = 0; i < 64; ++i) {
      float mv = s_m[nl * 64 + i];
      float hh = s_row[nl * 64 + i];
      gir = fmaf(mv, wihT[i * 193 + c], gir);
      giz = fmaf(mv, wihT[i * 193 + 64 + c], giz);
      gin = fmaf(mv, wihT[i * 193 + 128 + c], gin);
      ghr = fmaf(hh, whhT[i * 193 + c], ghr);
      ghz = fmaf(hh, whhT[i * 193 + 64 + c], ghz);
      ghn = fmaf(hh, whhT[i * 193 + 128 + c], ghn);
    }
    float r = 1.f / (1.f + __expf(-(gir + ghr)));
    float z = 1.f / (1.f + __expf(-(giz + ghz)));
    float nnv = tanhf(fmaf(r, ghn, gin));
    float hprev = s_row[nl * 64 + c];
    hv[(size_t)n * 64 + c] = (1.f - z) * nnv + z * hprev;
  }
}

// ---------------- K6: output head + normalize + readout accumulation
__global__ __launch_bounds__(64) void head_kernel(
    const float* __restrict__ hv, const float* __restrict__ x,
    const int* __restrict__ batch,
    const float* __restrict__ Wo1, const float* __restrict__ bo1,
    const float* __restrict__ Wo2, const float* __restrict__ bo2,
    float* __restrict__ feat, float* __restrict__ readout, float* __restrict__ cnt) {
  __shared__ float row[64];
  __shared__ float o1[64];
  int n = blockIdx.x;
  int t = threadIdx.x;
  row[t] = hv[(size_t)n * 64 + t];
  __syncthreads();
  float a = bo1[t];
  for (int i = 0; i < 64; ++i) a = fmaf(row[i], Wo1[i * 64 + t], a);
  o1[t] = fmaxf(a, 0.f);
  __syncthreads();
  float b = bo2[t];
  for (int i = 0; i < 64; ++i) b = fmaf(o1[i], Wo2[i * 64 + t], b);
  float xv = (t < NATOM) ? x[(size_t)n * NATOM + t] : 0.f;
  float sq = b * b + xv * xv;
  #pragma unroll
  for (int off = 1; off < 64; off <<= 1) sq += __shfl_xor(sq, off);
  float inv = 1.f / fmaxf(sqrtf(sq), 1e-12f);
  int bg = batch[n];
  float fo = b * inv;
  feat[(size_t)n * 90 + t] = fo;
  atomicAdd(&readout[bg * 90 + t], fo);
  if (t < NATOM) {
    float fx = xv * inv;
    feat[(size_t)n * 90 + 64 + t] = fx;
    atomicAdd(&readout[bg * 90 + 64 + t], fx);
  }
  if (t == 0) atomicAdd(&cnt[bg], 1.f);
}

// ---------------- K7: ratio = sigmoid(mean_readout @ Wp + bp)
__global__ __launch_bounds__(64) void ratio_kernel(
    const float* __restrict__ readout, const float* __restrict__ cnt,
    const float* __restrict__ Wp, const float* __restrict__ bp,
    float* __restrict__ ratio) {
  int g = threadIdx.x;  // 0..63
  float c = fmaxf(cnt[g], 1.f);
  float a = bp[0];
  for (int j = 0; j < 90; ++j) a = fmaf(readout[g * 90 + j] / c, Wp[j], a);
  ratio[g] = 1.f / (1.f + __expf(-a));
}

extern "C" void kernel_launch(void* const* d_in, const int* in_sizes, int n_in,
                              void* d_out, int out_size, void* d_ws, size_t ws_size,
                              hipStream_t stream) {
  const float* x      = (const float*)d_in[0];
  const int*   ei     = (const int*)  d_in[1];
  const float* ea     = (const float*)d_in[2];
  const int*   batch  = (const int*)  d_in[3];
  const float* W_in   = (const float*)d_in[4];
  const float* b_in   = (const float*)d_in[5];
  const float* We1    = (const float*)d_in[6];
  const float* be1    = (const float*)d_in[7];
  const float* We2    = (const float*)d_in[8];
  const float* be2    = (const float*)d_in[9];
  const float* W_root = (const float*)d_in[10];
  const float* b_conv = (const float*)d_in[11];
  const float* W_ih   = (const float*)d_in[12];
  const float* b_ih   = (const float*)d_in[13];
  const float* W_hh   = (const float*)d_in[14];
  const float* b_hh   = (const float*)d_in[15];
  const float* Wo1    = (const float*)d_in[16];
  const float* bo1    = (const float*)d_in[17];
  const float* Wo2    = (const float*)d_in[18];
  const float* bo2    = (const float*)d_in[19];
  const float* Wp     = (const float*)d_in[20];
  const float* bp     = (const float*)d_in[21];

  float* ws      = (float*)d_ws;
  float* U       = ws;                                   // NE*132  = 6,600,000
  float* h       = U + (size_t)NE * U_STRIDE;            // NN*64   = 1,600,000
  float* agg     = h + (size_t)NN * 64;                  // NN*64
  float* readout = agg + (size_t)NN * 64;                // 64*90
  float* cnt     = readout + 64 * 90;                    // 64
  // total ws: ~39.3 MB

  const int* srcp = ei;
  const int* dstp = ei + NE;
  float* feat  = (float*)d_out;
  float* ratio = feat + (size_t)NN * 90;

  hipMemsetAsync(readout, 0, (64 * 90 + 64) * sizeof(float), stream);
  edge_mlp_kernel<<<NE, 128, 0, stream>>>(ea, We1, be1, U);
  node_in_kernel<<<(NN * HID + 255) / 256, 256, 0, stream>>>(x, W_in, b_in, h);

  for (int it = 0; it < NUM_ITER; ++it) {
    hipMemsetAsync(agg, 0, (size_t)NN * 64 * sizeof(float), stream);
    edge_msg_kernel<<<(NE + EB - 1) / EB, 256, 0, stream>>>(U, h, srcp, dstp, We2, be2, agg);
    node_update_kernel<<<(NN + NPB - 1) / NPB, 256, 0, stream>>>(
        h, agg, W_root, b_conv, W_ih, b_ih, W_hh, b_hh);
  }

  head_kernel<<<NN, 64, 0, stream>>>(h, x, batch, Wo1, bo1, Wo2, bo2, feat, readout, cnt);
  ratio_kernel<<<1, 64, 0, stream>>>(readout, cnt, Wp, bp, ratio);
}

// Round 2
// 4131.189 us; speedup vs baseline: 1.0009x; 1.0009x over previous
//
#include <hip/hip_runtime.h>
#include <math.h>

#define NN 25000
#define NE 50000
#define NEP 50048     // edges padded to multiple of 64
#define NATOM 26
#define HID 64
#define NG 64
#define NUM_ITER 3
#define KE 160        // padded K (128 relu + 1.0 slot + 31 zeros)
#define KP 164        // LDS K stride: 82 dwords == 18 mod 32 -> conflict-free b64 frag reads
#define U_STRIDE 132  // fallback path
#define EB 64
#define NPB 32

typedef __attribute__((ext_vector_type(8))) short bf16x8;
typedef __attribute__((ext_vector_type(4))) float f32x4;
union FragU { bf16x8 v; ushort4 q[2]; };

static __device__ __forceinline__ ushort f2bf(float f) {
  unsigned u = __float_as_uint(f);
  unsigned r = (u + 0x7FFFu + ((u >> 16) & 1u)) >> 16;
  return (ushort)r;
}
static __device__ __forceinline__ float bf2f(ushort h) {
  return __uint_as_float(((unsigned)h) << 16);
}

// ==================== shared kernels (both paths) ====================

__global__ __launch_bounds__(256) void node_in_kernel(
    const float* __restrict__ x, const float* __restrict__ W_in,
    const float* __restrict__ b_in, float* __restrict__ h) {
  int idx = blockIdx.x * 256 + threadIdx.x;
  if (idx >= NN * HID) return;
  int n = idx >> 6, c = idx & 63;
  float acc = b_in[c];
  #pragma unroll
  for (int j = 0; j < NATOM; ++j) acc = fmaf(x[n * NATOM + j], W_in[j * HID + c], acc);
  h[idx] = fmaxf(acc, 0.f);
}

__global__ __launch_bounds__(256) void node_update_kernel(
    float* __restrict__ hv, const float* __restrict__ agg,
    const float* __restrict__ W_root, const float* __restrict__ b_conv,
    const float* __restrict__ W_ih, const float* __restrict__ b_ih,
    const float* __restrict__ W_hh, const float* __restrict__ b_hh) {
  __shared__ float wroot[64 * 64];
  __shared__ float wihT[64 * 193];
  __shared__ float whhT[64 * 193];
  __shared__ float s_row[NPB * 64];
  __shared__ float s_m[NPB * 64];
  int tid = threadIdx.x;
  int n0 = blockIdx.x * NPB;

  for (int idx = tid; idx < 64 * 16; idx += 256)
    ((float4*)wroot)[idx] = ((const float4*)W_root)[idx];
  for (int idx4 = tid; idx4 < 192 * 16; idx4 += 256) {
    int j = idx4 >> 4, i4 = (idx4 & 15) * 4;
    float4 a = ((const float4*)W_ih)[idx4];
    float4 b = ((const float4*)W_hh)[idx4];
    wihT[(i4 + 0) * 193 + j] = a.x; wihT[(i4 + 1) * 193 + j] = a.y;
    wihT[(i4 + 2) * 193 + j] = a.z; wihT[(i4 + 3) * 193 + j] = a.w;
    whhT[(i4 + 0) * 193 + j] = b.x; whhT[(i4 + 1) * 193 + j] = b.y;
    whhT[(i4 + 2) * 193 + j] = b.z; whhT[(i4 + 3) * 193 + j] = b.w;
  }
  for (int idx = tid; idx < NPB * 64; idx += 256) {
    int n = n0 + (idx >> 6);
    s_row[idx] = (n < NN) ? hv[(size_t)n * 64 + (idx & 63)] : 0.f;
  }
  __syncthreads();

  int c = tid & 63, g = tid >> 6;
  #pragma unroll
  for (int q = 0; q < 8; ++q) {
    int nl = g + 4 * q;
    int n = n0 + nl;
    float a = 0.f;
    for (int i = 0; i < 64; ++i) a = fmaf(s_row[nl * 64 + i], wroot[i * 64 + c], a);
    float val = 0.f;
    if (n < NN) val = fmaxf(a + agg[(size_t)n * 64 + c] + b_conv[c], 0.f);
    s_m[nl * 64 + c] = val;
  }
  __syncthreads();
  #pragma unroll
  for (int q = 0; q < 8; ++q) {
    int nl = g + 4 * q;
    int n = n0 + nl;
    if (n >= NN) continue;
    float gir = b_ih[c], giz = b_ih[64 + c], gin = b_ih[128 + c];
    float ghr = b_hh[c], ghz = b_hh[64 + c], ghn = b_hh[128 + c];
    for (int i = 0; i < 64; ++i) {
      float mv = s_m[nl * 64 + i];
      float hh = s_row[nl * 64 + i];
      gir = fmaf(mv, wihT[i * 193 + c], gir);
      giz = fmaf(mv, wihT[i * 193 + 64 + c], giz);
      gin = fmaf(mv, wihT[i * 193 + 128 + c], gin);
      ghr = fmaf(hh, whhT[i * 193 + c], ghr);
      ghz = fmaf(hh, whhT[i * 193 + 64 + c], ghz);
      ghn = fmaf(hh, whhT[i * 193 + 128 + c], ghn);
    }
    float r = 1.f / (1.f + __expf(-(gir + ghr)));
    float z = 1.f / (1.f + __expf(-(giz + ghz)));
    float nnv = tanhf(fmaf(r, ghn, gin));
    float hprev = s_row[nl * 64 + c];
    hv[(size_t)n * 64 + c] = (1.f - z) * nnv + z * hprev;
  }
}

__global__ __launch_bounds__(64) void head_kernel(
    const float* __restrict__ hv, const float* __restrict__ x,
    const int* __restrict__ batch,
    const float* __restrict__ Wo1, const float* __restrict__ bo1,
    const float* __restrict__ Wo2, const float* __restrict__ bo2,
    float* __restrict__ feat, float* __restrict__ readout, float* __restrict__ cnt) {
  __shared__ float row[64];
  __shared__ float o1[64];
  int n = blockIdx.x;
  int t = threadIdx.x;
  row[t] = hv[(size_t)n * 64 + t];
  __syncthreads();
  float a = bo1[t];
  for (int i = 0; i < 64; ++i) a = fmaf(row[i], Wo1[i * 64 + t], a);
  o1[t] = fmaxf(a, 0.f);
  __syncthreads();
  float b = bo2[t];
  for (int i = 0; i < 64; ++i) b = fmaf(o1[i], Wo2[i * 64 + t], b);
  float xv = (t < NATOM) ? x[(size_t)n * NATOM + t] : 0.f;
  float sq = b * b + xv * xv;
  #pragma unroll
  for (int off = 1; off < 64; off <<= 1) sq += __shfl_xor(sq, off);
  float inv = 1.f / fmaxf(sqrtf(sq), 1e-12f);
  int bg = batch[n];
  float fo = b * inv;
  feat[(size_t)n * 90 + t] = fo;
  atomicAdd(&readout[bg * 90 + t], fo);
  if (t < NATOM) {
    float fx = xv * inv;
    feat[(size_t)n * 90 + 64 + t] = fx;
    atomicAdd(&readout[bg * 90 + 64 + t], fx);
  }
  if (t == 0) atomicAdd(&cnt[bg], 1.f);
}

__global__ __launch_bounds__(64) void ratio_kernel(
    const float* __restrict__ readout, const float* __restrict__ cnt,
    const float* __restrict__ Wp, const float* __restrict__ bp,
    float* __restrict__ ratio) {
  int g = threadIdx.x;
  float c = fmaxf(cnt[g], 1.f);
  float a = bp[0];
  for (int j = 0; j < 90; ++j) a = fmaf(readout[g * 90 + j] / c, Wp[j], a);
  ratio[g] = 1.f / (1.f + __expf(-a));
}

// ==================== fast path: materialized bf16 Wedge ====================

// U = [relu(ea@We1+be1), 1.0, zeros] as bf16 rows of length KE
__global__ __launch_bounds__(128) void edge_mlp_bf16_kernel(
    const float* __restrict__ ea, const float* __restrict__ We1,
    const float* __restrict__ be1, ushort* __restrict__ U) {
  int e = blockIdx.x, t = threadIdx.x;
  float a0 = ea[e * 4 + 0], a1 = ea[e * 4 + 1], a2 = ea[e * 4 + 2], a3 = ea[e * 4 + 3];
  float v = be1[t];
  v = fmaf(a0, We1[t], v);
  v = fmaf(a1, We1[128 + t], v);
  v = fmaf(a2, We1[256 + t], v);
  v = fmaf(a3, We1[384 + t], v);
  U[(size_t)e * KE + t] = f2bf(fmaxf(v, 0.f));
  if (t == 0) U[(size_t)e * KE + 128] = 0x3F80;  // bf16 1.0 (be2 fold)
}

// Bt[n][k] = We2ext[k][n] in bf16 (row 128 = be2, 129..159 = 0)
__global__ __launch_bounds__(256) void we2t_kernel(
    const float* __restrict__ We2, const float* __restrict__ be2,
    ushort* __restrict__ Bt) {
  int k = blockIdx.x;  // 0..159
  for (int n = threadIdx.x; n < 4096; n += 256) {
    float v = (k < 128) ? We2[(size_t)k * 4096 + n] : (k == 128 ? be2[n] : 0.f);
    Bt[(size_t)n * KE + k] = f2bf(v);
  }
}

// C[NEP][4096] = U[NEP][KE] @ B[KE][4096], MFMA 16x16x32 bf16.
// BM=64, BN=128, full K resident. 4 waves as 2x2: wave tile 32x64.
__global__ __launch_bounds__(256, 2) void wedge_gemm_kernel(
    const ushort* __restrict__ U, const ushort* __restrict__ Bt,
    ushort* __restrict__ C) {
  __shared__ ushort At[64 * KP];    // 20,992 B
  __shared__ ushort Bs[128 * KP];   // 41,984 B
  int tid = threadIdx.x;
  int ntile = blockIdx.x & 31;
  int mtile = blockIdx.x >> 5;
  int m0 = mtile * 64, n0 = ntile * 128;

  #pragma unroll
  for (int q = 0; q < 5; ++q) {          // A: 64x160 = 1280 chunks of 8
    int flat = (q * 256 + tid) * 8;
    int r = flat / KE, c = flat % KE;
    const ushort4* gp = (const ushort4*)(U + (size_t)(m0 + r) * KE + c);
    *(ushort4*)&At[r * KP + c] = gp[0];
    *(ushort4*)&At[r * KP + c + 4] = gp[1];
  }
  #pragma unroll
  for (int q = 0; q < 10; ++q) {         // B(t): 128x160 = 2560 chunks
    int flat = (q * 256 + tid) * 8;
    int r = flat / KE, c = flat % KE;
    const ushort4* gp = (const ushort4*)(Bt + (size_t)(n0 + r) * KE + c);
    *(ushort4*)&Bs[r * KP + c] = gp[0];
    *(ushort4*)&Bs[r * KP + c + 4] = gp[1];
  }
  __syncthreads();

  int lane = tid & 63, wid = tid >> 6;
  int wr = wid >> 1, wc = wid & 1;
  int l15 = lane & 15, lg = lane >> 4;

  f32x4 acc[2][4];
  #pragma unroll
  for (int i = 0; i < 2; ++i)
    #pragma unroll
    for (int j = 0; j < 4; ++j) acc[i][j] = (f32x4){0.f, 0.f, 0.f, 0.f};

  #pragma unroll
  for (int ks = 0; ks < 5; ++ks) {
    int k0 = ks * 32;
    // frag k-map (split halves): elem j -> k = k0 + 16*(j>>2) + 4*lg + (j&3)
    FragU af[2], bfr[4];
    #pragma unroll
    for (int fm = 0; fm < 2; ++fm) {
      const ushort* p = &At[(wr * 32 + fm * 16 + l15) * KP + k0 + lg * 4];
      af[fm].q[0] = *(const ushort4*)p;
      af[fm].q[1] = *(const ushort4*)(p + 16);
    }
    #pragma unroll
    for (int fn = 0; fn < 4; ++fn) {
      const ushort* p = &Bs[(wc * 64 + fn * 16 + l15) * KP + k0 + lg * 4];
      bfr[fn].q[0] = *(const ushort4*)p;
      bfr[fn].q[1] = *(const ushort4*)(p + 16);
    }
    #pragma unroll
    for (int fm = 0; fm < 2; ++fm)
      #pragma unroll
      for (int fn = 0; fn < 4; ++fn)
        acc[fm][fn] = __builtin_amdgcn_mfma_f32_16x16x32_bf16(
            af[fm].v, bfr[fn].v, acc[fm][fn], 0, 0, 0);
  }

  // C/D: col = lane&15, row = (lane>>4)*4 + reg  [m89]
  #pragma unroll
  for (int fm = 0; fm < 2; ++fm) {
    int rowb = m0 + wr * 32 + fm * 16 + lg * 4;
    #pragma unroll
    for (int fn = 0; fn < 4; ++fn) {
      int col = n0 + wc * 64 + fn * 16 + l15;
      #pragma unroll
      for (int rr = 0; rr < 4; ++rr)
        C[(size_t)(rowb + rr) * 4096 + col] = f2bf(acc[fm][fn][rr]);
    }
  }
}

// per-edge msg = s[e] @ Wedge[e] (64x64), fused scatter-add. Wave per edge.
__global__ __launch_bounds__(256) void bmm_scatter_kernel(
    const ushort* __restrict__ W, const float* __restrict__ hv,
    const int* __restrict__ src, const int* __restrict__ dst,
    float* __restrict__ agg) {
  __shared__ float s_s[4][64];
  int lane = threadIdx.x & 63, w = threadIdx.x >> 6;
  int e = blockIdx.x * 4 + w;  // grid exact: NE/4
  s_s[w][lane] = hv[(size_t)src[e] * 64 + lane];
  __syncthreads();
  int r = lane >> 3, c = lane & 7;   // i-subrow, o-block
  float acc[8];
  #pragma unroll
  for (int j = 0; j < 8; ++j) acc[j] = 0.f;
  const ushort* wp = W + (size_t)e * 4096;
  #pragma unroll
  for (int stp = 0; stp < 8; ++stp) {
    float sv = s_s[w][stp * 8 + r];
    const ushort4* p = (const ushort4*)(wp + (size_t)stp * 512 + r * 64 + c * 8);
    ushort4 w0 = p[0], w1 = p[1];
    acc[0] = fmaf(sv, bf2f(w0.x), acc[0]);
    acc[1] = fmaf(sv, bf2f(w0.y), acc[1]);
    acc[2] = fmaf(sv, bf2f(w0.z), acc[2]);
    acc[3] = fmaf(sv, bf2f(w0.w), acc[3]);
    acc[4] = fmaf(sv, bf2f(w1.x), acc[4]);
    acc[5] = fmaf(sv, bf2f(w1.y), acc[5]);
    acc[6] = fmaf(sv, bf2f(w1.z), acc[6]);
    acc[7] = fmaf(sv, bf2f(w1.w), acc[7]);
  }
  #pragma unroll
  for (int j = 0; j < 8; ++j) {
    acc[j] += __shfl_xor(acc[j], 8);
    acc[j] += __shfl_xor(acc[j], 16);
    acc[j] += __shfl_xor(acc[j], 32);
  }
  if (r == 0) {
    float* ap = agg + (size_t)dst[e] * 64 + c * 8;
    #pragma unroll
    for (int j = 0; j < 8; ++j) atomicAdd(ap + j, acc[j]);
  }
}

// ==================== fallback path (round-1, fp32 fused) ====================

__global__ __launch_bounds__(128) void edge_mlp_kernel(
    const float* __restrict__ ea, const float* __restrict__ We1,
    const float* __restrict__ be1, float* __restrict__ U) {
  int e = blockIdx.x;
  int t = threadIdx.x;
  float a0 = ea[e * 4 + 0], a1 = ea[e * 4 + 1], a2 = ea[e * 4 + 2], a3 = ea[e * 4 + 3];
  float v = be1[t];
  v = fmaf(a0, We1[t], v);
  v = fmaf(a1, We1[128 + t], v);
  v = fmaf(a2, We1[256 + t], v);
  v = fmaf(a3, We1[384 + t], v);
  U[(size_t)e * U_STRIDE + t] = fmaxf(v, 0.f);
  if (t == 0) {
    U[(size_t)e * U_STRIDE + 128] = 1.f;
    U[(size_t)e * U_STRIDE + 129] = 0.f;
    U[(size_t)e * U_STRIDE + 130] = 0.f;
    U[(size_t)e * U_STRIDE + 131] = 0.f;
  }
}

__global__ __launch_bounds__(256) void edge_msg_kernel(
    const float* __restrict__ U, const float* __restrict__ hv,
    const int* __restrict__ src, const int* __restrict__ dst,
    const float* __restrict__ We2, const float* __restrict__ be2,
    float* __restrict__ agg) {
  __shared__ float s_tile[EB * HID];
  __shared__ float w_chunk[4 * 4096];
  int tid = threadIdx.x;
  int e0 = blockIdx.x * EB;

  for (int idx = tid; idx < EB * HID; idx += 256) {
    int eg = e0 + (idx >> 6);
    s_tile[idx] = (eg < NE) ? hv[(size_t)src[eg] * HID + (idx & 63)] : 0.f;
  }
  int o = tid & 63, g = tid >> 6;
  float acc[16];
  #pragma unroll
  for (int j = 0; j < 16; ++j) acc[j] = 0.f;
  __syncthreads();

  for (int kc = 0; kc < U_STRIDE; kc += 4) {
    for (int idx = tid; idx < 4 * 1024; idx += 256) {
      int kk = idx >> 10, c4 = idx & 1023;
      int k = kc + kk;
      float4 wv;
      if (k < 128)       wv = ((const float4*)We2)[(size_t)k * 1024 + c4];
      else if (k == 128) wv = ((const float4*)be2)[c4];
      else               wv = make_float4(0.f, 0.f, 0.f, 0.f);
      ((float4*)w_chunk)[idx] = wv;
    }
    __syncthreads();

    float pacc[16][4];
    #pragma unroll
    for (int j = 0; j < 16; ++j) {
      #pragma unroll
      for (int kk = 0; kk < 4; ++kk) pacc[j][kk] = 0.f;
    }
    #pragma unroll 2
    for (int i = 0; i < 64; ++i) {
      float w0 = w_chunk[          i * 64 + o];
      float w1 = w_chunk[ 4096 +   i * 64 + o];
      float w2 = w_chunk[ 8192 +   i * 64 + o];
      float w3 = w_chunk[12288 +   i * 64 + o];
      #pragma unroll
      for (int j = 0; j < 16; ++j) {
        float sv = s_tile[(g + 4 * j) * 64 + i];
        pacc[j][0] = fmaf(sv, w0, pacc[j][0]);
        pacc[j][1] = fmaf(sv, w1, pacc[j][1]);
        pacc[j][2] = fmaf(sv, w2, pacc[j][2]);
        pacc[j][3] = fmaf(sv, w3, pacc[j][3]);
      }
    }
    #pragma unroll
    for (int j = 0; j < 16; ++j) {
      int eg = e0 + g + 4 * j;
      if (eg < NE) {
        const float* up = U + (size_t)eg * U_STRIDE + kc;
        acc[j] = fmaf(up[0], pacc[j][0], acc[j]);
        acc[j] = fmaf(up[1], pacc[j][1], acc[j]);
        acc[j] = fmaf(up[2], pacc[j][2], acc[j]);
        acc[j] = fmaf(up[3], pacc[j][3], acc[j]);
      }
    }
    __syncthreads();
  }
  #pragma unroll
  for (int j = 0; j < 16; ++j) {
    int eg = e0 + g + 4 * j;
    if (eg < NE) atomicAdd(&agg[(size_t)dst[eg] * HID + o], acc[j]);
  }
}

// ==================== launcher ====================

extern "C" void kernel_launch(void* const* d_in, const int* in_sizes, int n_in,
                              void* d_out, int out_size, void* d_ws, size_t ws_size,
                              hipStream_t stream) {
  const float* x      = (const float*)d_in[0];
  const int*   ei     = (const int*)  d_in[1];
  const float* ea     = (const float*)d_in[2];
  const int*   batch  = (const int*)  d_in[3];
  const float* W_in   = (const float*)d_in[4];
  const float* b_in   = (const float*)d_in[5];
  const float* We1    = (const float*)d_in[6];
  const float* be1    = (const float*)d_in[7];
  const float* We2    = (const float*)d_in[8];
  const float* be2    = (const float*)d_in[9];
  const float* W_root = (const float*)d_in[10];
  const float* b_conv = (const float*)d_in[11];
  const float* W_ih   = (const float*)d_in[12];
  const float* b_ih   = (const float*)d_in[13];
  const float* W_hh   = (const float*)d_in[14];
  const float* b_hh   = (const float*)d_in[15];
  const float* Wo1    = (const float*)d_in[16];
  const float* bo1    = (const float*)d_in[17];
  const float* Wo2    = (const float*)d_in[18];
  const float* bo2    = (const float*)d_in[19];
  const float* Wp     = (const float*)d_in[20];
  const float* bp     = (const float*)d_in[21];

  const int* srcp = ei;
  const int* dstp = ei + NE;
  float* feat  = (float*)d_out;
  float* ratio = feat + (size_t)NN * 90;

  // fast-path ws layout (bytes)
  const size_t oU    = 0;                       // bf16 U [NEP][KE]      16,015,360
  const size_t oBt   = 16015360;                // bf16 Bt [4096][KE]     1,310,720
  const size_t oW    = 17326080;                // bf16 Wedge [NEP][4096] 409,993,216
  const size_t oH    = 427319296;               // f32 h                  6,400,000
  const size_t oAgg  = 433719296;               // f32 agg                6,400,000
  const size_t oRead = 440119296;               // f32 readout            23,040
  const size_t oCnt  = 440142336;               // f32 cnt                256
  const size_t NEED  = 440142592;

  if (ws_size >= NEED) {
    char* wsb = (char*)d_ws;
    ushort* U    = (ushort*)(wsb + oU);
    ushort* Bt   = (ushort*)(wsb + oBt);
    ushort* Wdg  = (ushort*)(wsb + oW);
    float* h     = (float*)(wsb + oH);
    float* agg   = (float*)(wsb + oAgg);
    float* readout = (float*)(wsb + oRead);
    float* cnt   = (float*)(wsb + oCnt);

    hipMemsetAsync(readout, 0, 23040 + 256, stream);
    hipMemsetAsync((void*)U, 0, 16015360, stream);
    edge_mlp_bf16_kernel<<<NE, 128, 0, stream>>>(ea, We1, be1, U);
    we2t_kernel<<<KE, 256, 0, stream>>>(We2, be2, Bt);
    node_in_kernel<<<(NN * HID + 255) / 256, 256, 0, stream>>>(x, W_in, b_in, h);
    wedge_gemm_kernel<<<(NEP / 64) * 32, 256, 0, stream>>>(U, Bt, Wdg);

    for (int it = 0; it < NUM_ITER; ++it) {
      hipMemsetAsync(agg, 0, (size_t)NN * 64 * sizeof(float), stream);
      bmm_scatter_kernel<<<NE / 4, 256, 0, stream>>>(Wdg, h, srcp, dstp, agg);
      node_update_kernel<<<(NN + NPB - 1) / NPB, 256, 0, stream>>>(
          h, agg, W_root, b_conv, W_ih, b_ih, W_hh, b_hh);
    }
    head_kernel<<<NN, 64, 0, stream>>>(h, x, batch, Wo1, bo1, Wo2, bo2, feat, readout, cnt);
    ratio_kernel<<<1, 64, 0, stream>>>(readout, cnt, Wp, bp, ratio);
  } else {
    // fallback: round-1 fp32 fused path (39.3 MB ws)
    float* ws      = (float*)d_ws;
    float* U       = ws;
    float* h       = U + (size_t)NE * U_STRIDE;
    float* agg     = h + (size_t)NN * 64;
    float* readout = agg + (size_t)NN * 64;
    float* cnt     = readout + 64 * 90;

    hipMemsetAsync(readout, 0, (64 * 90 + 64) * sizeof(float), stream);
    edge_mlp_kernel<<<NE, 128, 0, stream>>>(ea, We1, be1, U);
    node_in_kernel<<<(NN * HID + 255) / 256, 256, 0, stream>>>(x, W_in, b_in, h);

    for (int it = 0; it < NUM_ITER; ++it) {
      hipMemsetAsync(agg, 0, (size_t)NN * 64 * sizeof(float), stream);
      edge_msg_kernel<<<(NE + EB - 1) / EB, 256, 0, stream>>>(U, h, srcp, dstp, We2, be2, agg);
      node_update_kernel<<<(NN + NPB - 1) / NPB, 256, 0, stream>>>(
          h, agg, W_root, b_conv, W_ih, b_ih, W_hh, b_hh);
    }
    head_kernel<<<NN, 64, 0, stream>>>(h, x, batch, Wo1, bo1, Wo2, bo2, feat, readout, cnt);
    ratio_kernel<<<1, 64, 0, stream>>>(readout, cnt, Wp, bp, ratio);
  }
}

// Round 4
// 862.547 us; speedup vs baseline: 4.7937x; 4.7895x over previous
//
#include <hip/hip_runtime.h>
#include <math.h>

#define NN 25000
#define NE 50000
#define NEP2 50176            // 196 * 256 edges (padded)
#define NBLK 196
#define NATOM 26
#define NUM_ITER 3
#define NCH 33                // K' = 33 chunks x 256 (4 k-values x 64 i's)
#define NPB 32

typedef __attribute__((ext_vector_type(8))) short bf16x8;
typedef __attribute__((ext_vector_type(8))) unsigned short ushort8_t;
typedef __attribute__((ext_vector_type(4))) float f32x4;

static __device__ __forceinline__ ushort f2bf(float f) {
  unsigned u = __float_as_uint(f);
  unsigned r = (u + 0x7FFFu + ((u >> 16) & 1u)) >> 16;
  return (ushort)r;
}
static __device__ __forceinline__ unsigned cvt_pk_bf16(float a, float b) {
  unsigned r;
  asm("v_cvt_pk_bf16_f32 %0, %1, %2" : "=v"(r) : "v"(a), "v"(b));
  return r;
}
static __device__ __forceinline__ float bflo(unsigned u) { return __uint_as_float(u << 16); }
static __device__ __forceinline__ float bfhi(unsigned u) { return __uint_as_float(u & 0xFFFF0000u); }

// ---------------- U pack: relu(ea@We1+be1) -> Upkt[g][e][4] bf16 (k-group-major)
__global__ __launch_bounds__(256) void edge_mlp_pack_kernel(
    const float* __restrict__ ea, const float* __restrict__ We1,
    const float* __restrict__ be1, ushort* __restrict__ Upkt) {
  int t = threadIdx.x;
  int el = t & 63, seg = t >> 6;
  int e = blockIdx.x * 64 + el;       // grid 784 -> e < 50176
  bool valid = (e < NE);
  float a0 = 0.f, a1 = 0.f, a2 = 0.f, a3 = 0.f;
  if (valid) { a0 = ea[e * 4]; a1 = ea[e * 4 + 1]; a2 = ea[e * 4 + 2]; a3 = ea[e * 4 + 3]; }
  #pragma unroll
  for (int q = 0; q < 8; ++q) {
    int g = seg * 8 + q;              // k-group 0..31 (k = 4g..4g+3 < 128)
    ushort out[4];
    #pragma unroll
    for (int kk = 0; kk < 4; ++kk) {
      int k = g * 4 + kk;
      float v = be1[k];
      v = fmaf(a0, We1[k], v);
      v = fmaf(a1, We1[128 + k], v);
      v = fmaf(a2, We1[256 + k], v);
      v = fmaf(a3, We1[384 + k], v);
      out[kk] = valid ? f2bf(fmaxf(v, 0.f)) : (ushort)0;
    }
    *(ushort4*)&Upkt[((size_t)g * NEP2 + e) * 4] = *(ushort4*)out;
  }
  if (seg == 0) {                     // g=32: k=128 -> 1.0 (be2 fold), 129..131 -> 0
    ushort out[4] = {(ushort)(valid ? 0x3F80 : 0), 0, 0, 0};
    *(ushort4*)&Upkt[((size_t)32 * NEP2 + e) * 4] = *(ushort4*)out;
  }
}

// ---------------- B pack: We2ext[f][o] -> per-lane fragment order
// Bpk[((c*8+ks)*4+nt)*64 + lane][8]; elem j at f = c*256+ks*32+kl(lg,j), o = nt*16+l15
__global__ __launch_bounds__(256) void bpk_pack_kernel(
    const float* __restrict__ We2, const float* __restrict__ be2,
    ushort* __restrict__ Bpk) {
  int idx = blockIdx.x * 256 + threadIdx.x;   // 264 blocks -> 67584 = 33*8*4*64
  int lane = idx & 63;
  int nt = (idx >> 6) & 3;
  int ks = (idx >> 8) & 7;
  int c = idx >> 11;
  int l15 = lane & 15, lg = lane >> 4;
  int o = nt * 16 + l15;
  ushort v[8];
  #pragma unroll
  for (int j = 0; j < 8; ++j) {
    int kl = (j < 4) ? (4 * lg + j) : (12 + 4 * lg + j);   // split-halves k-map
    int f = c * 256 + ks * 32 + kl;
    int k = f >> 6, i = f & 63;
    float wv = 0.f;
    if (k < 128) wv = We2[(size_t)k * 4096 + i * 64 + o];
    else if (k == 128) wv = be2[i * 64 + o];
    v[j] = f2bf(wv);
  }
  *(ushort8_t*)(Bpk + (size_t)idx * 8) = *(ushort8_t*)v;
}

// ---------------- fused edge-message GEMM: msg = (U (x) s) @ We2flat, + scatter
// 512 threads = 8 waves; wave tile = 32 edge-rows (mt=0..1), full N=64 (nt=0..3).
__global__ __launch_bounds__(512, 1) void edge_rgemm_kernel(
    const ushort* __restrict__ Upkt, const ushort* __restrict__ Bpk,
    const float* __restrict__ hv, const int* __restrict__ src,
    const int* __restrict__ dst, float* __restrict__ agg) {
  __shared__ ushort sB[2][16384];   // 2 x 32KB frag-packed B chunk (2048 frags x 8)
  __shared__ ushort sU[2][1024];    // 2 x 2KB U chunk [256 e][4 k]
  __shared__ ushort sS[256][72];    // s bf16, padded row
  int tid = threadIdx.x;            // 0..511
  int lane = tid & 63, w = tid >> 6;
  int l15 = lane & 15, lg = lane >> 4;
  int e0 = blockIdx.x * 256;

  // stage s = bf16(h[src[e]])
  #pragma unroll
  for (int r = 0; r < 8; ++r) {
    int idx = r * 512 + tid;        // 0..4095 = 256 rows x 16 float4-parts
    int el = idx >> 4, part = idx & 15;
    int e = e0 + el;
    float4 v = make_float4(0.f, 0.f, 0.f, 0.f);
    if (e < NE) v = ((const float4*)hv)[(size_t)src[e] * 16 + part];
    unsigned lo = cvt_pk_bf16(v.x, v.y);
    unsigned hi = cvt_pk_bf16(v.z, v.w);
    *(uint2*)&sS[el][part * 4] = make_uint2(lo, hi);
  }

  // prologue: stage chunk 0 (ALL 2048 fragments: 512 threads x 4)
  ushort8_t rB[4]; uint2 rU;
  #pragma unroll
  for (int r = 0; r < 4; ++r)
    rB[r] = *(const ushort8_t*)(Bpk + ((size_t)r * 512 + tid) * 8);
  if (tid < 256) rU = *(const uint2*)(Upkt + (size_t)e0 * 4 + tid * 4);
  #pragma unroll
  for (int r = 0; r < 4; ++r)
    *(ushort8_t*)&sB[0][((size_t)r * 512 + tid) * 8] = rB[r];
  if (tid < 256) *(uint2*)&sU[0][tid * 4] = rU;
  __syncthreads();

  // per-wave s fragments: row = w*32 + mt*16 + l15, i = p*32 + g*16 + 4*lg
  float4 sreg[2][2][2];
  #pragma unroll
  for (int mt = 0; mt < 2; ++mt)
    #pragma unroll
    for (int p = 0; p < 2; ++p)
      #pragma unroll
      for (int g = 0; g < 2; ++g) {
        uint2 d = *(const uint2*)&sS[w * 32 + mt * 16 + l15][p * 32 + g * 16 + 4 * lg];
        sreg[mt][p][g] = make_float4(bflo(d.x), bfhi(d.x), bflo(d.y), bfhi(d.y));
      }

  f32x4 acc[2][4];
  #pragma unroll
  for (int mt = 0; mt < 2; ++mt)
    #pragma unroll
    for (int nt = 0; nt < 4; ++nt) acc[mt][nt] = (f32x4){0.f, 0.f, 0.f, 0.f};

  for (int c = 0; c < NCH; ++c) {
    int cur = c & 1;
    bool more = (c + 1 < NCH);
    if (more) {  // T14: issue next-chunk loads early
      const ushort* bs = Bpk + (size_t)(c + 1) * 16384;
      #pragma unroll
      for (int r = 0; r < 4; ++r)
        rB[r] = *(const ushort8_t*)(bs + ((size_t)r * 512 + tid) * 8);
      if (tid < 256)
        rU = *(const uint2*)(Upkt + ((size_t)(c + 1) * NEP2 + e0) * 4 + tid * 4);
    }
    float uu[2][4];
    #pragma unroll
    for (int mt = 0; mt < 2; ++mt) {
      uint2 d = *(const uint2*)&sU[cur][(w * 32 + mt * 16 + l15) * 4];
      uu[mt][0] = bflo(d.x); uu[mt][1] = bfhi(d.x);
      uu[mt][2] = bflo(d.y); uu[mt][3] = bfhi(d.y);
    }
    #pragma unroll
    for (int ks = 0; ks < 8; ++ks) {
      int p = ks & 1, ku = ks >> 1;
      bf16x8 bfr[4];
      #pragma unroll
      for (int nt = 0; nt < 4; ++nt)
        bfr[nt] = *(const bf16x8*)&sB[cur][(((size_t)ks * 4 + nt) * 64 + lane) * 8];
      #pragma unroll
      for (int mt = 0; mt < 2; ++mt) {
        float u = uu[mt][ku];
        float4 s0 = sreg[mt][p][0], s1 = sreg[mt][p][1];
        union { bf16x8 v; unsigned u32[4]; } af;
        af.u32[0] = cvt_pk_bf16(s0.x * u, s0.y * u);
        af.u32[1] = cvt_pk_bf16(s0.z * u, s0.w * u);
        af.u32[2] = cvt_pk_bf16(s1.x * u, s1.y * u);
        af.u32[3] = cvt_pk_bf16(s1.z * u, s1.w * u);
        #pragma unroll
        for (int nt = 0; nt < 4; ++nt)
          acc[mt][nt] = __builtin_amdgcn_mfma_f32_16x16x32_bf16(af.v, bfr[nt], acc[mt][nt], 0, 0, 0);
      }
    }
    if (more) {  // write-late into the other buffer
      int nb = cur ^ 1;
      #pragma unroll
      for (int r = 0; r < 4; ++r)
        *(ushort8_t*)&sB[nb][((size_t)r * 512 + tid) * 8] = rB[r];
      if (tid < 256) *(uint2*)&sU[nb][tid * 4] = rU;
    }
    __syncthreads();
  }

  // scatter: D row (within 16-tile) = lg*4 + rr, col = nt*16 + l15
  #pragma unroll
  for (int mt = 0; mt < 2; ++mt) {
    #pragma unroll
    for (int rr = 0; rr < 4; ++rr) {
      int e = e0 + w * 32 + mt * 16 + lg * 4 + rr;
      if (e < NE) {
        int d = dst[e];
        #pragma unroll
        for (int nt = 0; nt < 4; ++nt)
          atomicAdd(&agg[(size_t)d * 64 + nt * 16 + l15], acc[mt][nt][rr]);
      }
    }
  }
}

// ---------------- node input transform
__global__ __launch_bounds__(256) void node_in_kernel(
    const float* __restrict__ x, const float* __restrict__ W_in,
    const float* __restrict__ b_in, float* __restrict__ h) {
  int idx = blockIdx.x * 256 + threadIdx.x;
  if (idx >= NN * 64) return;
  int n = idx >> 6, c = idx & 63;
  float acc = b_in[c];
  #pragma unroll
  for (int j = 0; j < NATOM; ++j) acc = fmaf(x[n * NATOM + j], W_in[j * 64 + c], acc);
  h[idx] = fmaxf(acc, 0.f);
}

// ---------------- m = relu(h@W_root + agg + b_conv); GRU -> h (in place)
__global__ __launch_bounds__(256) void node_update_kernel(
    float* __restrict__ hv, const float* __restrict__ agg,
    const float* __restrict__ W_root, const float* __restrict__ b_conv,
    const float* __restrict__ W_ih, const float* __restrict__ b_ih,
    const float* __restrict__ W_hh, const float* __restrict__ b_hh) {
  __shared__ float wroot[64 * 64];
  __shared__ float wihT[64 * 193];
  __shared__ float whhT[64 * 193];
  __shared__ float s_row[NPB * 64];
  __shared__ float s_m[NPB * 64];
  int tid = threadIdx.x;
  int n0 = blockIdx.x * NPB;

  for (int idx = tid; idx < 64 * 16; idx += 256)
    ((float4*)wroot)[idx] = ((const float4*)W_root)[idx];
  for (int idx4 = tid; idx4 < 192 * 16; idx4 += 256) {
    int j = idx4 >> 4, i4 = (idx4 & 15) * 4;
    float4 a = ((const float4*)W_ih)[idx4];
    float4 b = ((const float4*)W_hh)[idx4];
    wihT[(i4 + 0) * 193 + j] = a.x; wihT[(i4 + 1) * 193 + j] = a.y;
    wihT[(i4 + 2) * 193 + j] = a.z; wihT[(i4 + 3) * 193 + j] = a.w;
    whhT[(i4 + 0) * 193 + j] = b.x; whhT[(i4 + 1) * 193 + j] = b.y;
    whhT[(i4 + 2) * 193 + j] = b.z; whhT[(i4 + 3) * 193 + j] = b.w;
  }
  for (int idx = tid; idx < NPB * 64; idx += 256) {
    int n = n0 + (idx >> 6);
    s_row[idx] = (n < NN) ? hv[(size_t)n * 64 + (idx & 63)] : 0.f;
  }
  __syncthreads();

  int c = tid & 63, g = tid >> 6;
  #pragma unroll
  for (int q = 0; q < 8; ++q) {
    int nl = g + 4 * q;
    int n = n0 + nl;
    float a = 0.f;
    for (int i = 0; i < 64; ++i) a = fmaf(s_row[nl * 64 + i], wroot[i * 64 + c], a);
    float val = 0.f;
    if (n < NN) val = fmaxf(a + agg[(size_t)n * 64 + c] + b_conv[c], 0.f);
    s_m[nl * 64 + c] = val;
  }
  __syncthreads();
  #pragma unroll
  for (int q = 0; q < 8; ++q) {
    int nl = g + 4 * q;
    int n = n0 + nl;
    if (n >= NN) continue;
    float gir = b_ih[c], giz = b_ih[64 + c], gin = b_ih[128 + c];
    float ghr = b_hh[c], ghz = b_hh[64 + c], ghn = b_hh[128 + c];
    for (int i = 0; i < 64; ++i) {
      float mv = s_m[nl * 64 + i];
      float hh = s_row[nl * 64 + i];
      gir = fmaf(mv, wihT[i * 193 + c], gir);
      giz = fmaf(mv, wihT[i * 193 + 64 + c], giz);
      gin = fmaf(mv, wihT[i * 193 + 128 + c], gin);
      ghr = fmaf(hh, whhT[i * 193 + c], ghr);
      ghz = fmaf(hh, whhT[i * 193 + 64 + c], ghz);
      ghn = fmaf(hh, whhT[i * 193 + 128 + c], ghn);
    }
    float r = 1.f / (1.f + __expf(-(gir + ghr)));
    float z = 1.f / (1.f + __expf(-(giz + ghz)));
    float nnv = tanhf(fmaf(r, ghn, gin));
    float hprev = s_row[nl * 64 + c];
    hv[(size_t)n * 64 + c] = (1.f - z) * nnv + z * hprev;
  }
}

// ---------------- head + normalize + readout
__global__ __launch_bounds__(64) void head_kernel(
    const float* __restrict__ hv, const float* __restrict__ x,
    const int* __restrict__ batch,
    const float* __restrict__ Wo1, const float* __restrict__ bo1,
    const float* __restrict__ Wo2, const float* __restrict__ bo2,
    float* __restrict__ feat, float* __restrict__ readout, float* __restrict__ cnt) {
  __shared__ float row[64];
  __shared__ float o1[64];
  int n = blockIdx.x;
  int t = threadIdx.x;
  row[t] = hv[(size_t)n * 64 + t];
  __syncthreads();
  float a = bo1[t];
  for (int i = 0; i < 64; ++i) a = fmaf(row[i], Wo1[i * 64 + t], a);
  o1[t] = fmaxf(a, 0.f);
  __syncthreads();
  float b = bo2[t];
  for (int i = 0; i < 64; ++i) b = fmaf(o1[i], Wo2[i * 64 + t], b);
  float xv = (t < NATOM) ? x[(size_t)n * NATOM + t] : 0.f;
  float sq = b * b + xv * xv;
  #pragma unroll
  for (int off = 1; off < 64; off <<= 1) sq += __shfl_xor(sq, off);
  float inv = 1.f / fmaxf(sqrtf(sq), 1e-12f);
  int bg = batch[n];
  float fo = b * inv;
  feat[(size_t)n * 90 + t] = fo;
  atomicAdd(&readout[bg * 90 + t], fo);
  if (t < NATOM) {
    float fx = xv * inv;
    feat[(size_t)n * 90 + 64 + t] = fx;
    atomicAdd(&readout[bg * 90 + 64 + t], fx);
  }
  if (t == 0) atomicAdd(&cnt[bg], 1.f);
}

__global__ __launch_bounds__(64) void ratio_kernel(
    const float* __restrict__ readout, const float* __restrict__ cnt,
    const float* __restrict__ Wp, const float* __restrict__ bp,
    float* __restrict__ ratio) {
  int g = threadIdx.x;
  float c = fmaxf(cnt[g], 1.f);
  float a = bp[0];
  for (int j = 0; j < 90; ++j) a = fmaf(readout[g * 90 + j] / c, Wp[j], a);
  ratio[g] = 1.f / (1.f + __expf(-a));
}

// ==================== launcher ====================

extern "C" void kernel_launch(void* const* d_in, const int* in_sizes, int n_in,
                              void* d_out, int out_size, void* d_ws, size_t ws_size,
                              hipStream_t stream) {
  const float* x      = (const float*)d_in[0];
  const int*   ei     = (const int*)  d_in[1];
  const float* ea     = (const float*)d_in[2];
  const int*   batch  = (const int*)  d_in[3];
  const float* W_in   = (const float*)d_in[4];
  const float* b_in   = (const float*)d_in[5];
  const float* We1    = (const float*)d_in[6];
  const float* be1    = (const float*)d_in[7];
  const float* We2    = (const float*)d_in[8];
  const float* be2    = (const float*)d_in[9];
  const float* W_root = (const float*)d_in[10];
  const float* b_conv = (const float*)d_in[11];
  const float* W_ih   = (const float*)d_in[12];
  const float* b_ih   = (const float*)d_in[13];
  const float* W_hh   = (const float*)d_in[14];
  const float* b_hh   = (const float*)d_in[15];
  const float* Wo1    = (const float*)d_in[16];
  const float* bo1    = (const float*)d_in[17];
  const float* Wo2    = (const float*)d_in[18];
  const float* bo2    = (const float*)d_in[19];
  const float* Wp     = (const float*)d_in[20];
  const float* bp     = (const float*)d_in[21];

  const int* srcp = ei;
  const int* dstp = ei + NE;
  float* feat  = (float*)d_out;
  float* ratio = feat + (size_t)NN * 90;

  // ws layout (bytes): total ~27.2 MB (round-1 proved >= 39.3 MB available)
  char* wsb = (char*)d_ws;
  ushort* Upkt   = (ushort*)(wsb + 0);            // 33*50176*4*2  = 13,246,464
  ushort* Bpk    = (ushort*)(wsb + 13246464);     // 33*8*4*64*8*2 =  1,081,344
  float*  h      = (float*) (wsb + 14327808);     // 6,400,000
  float*  agg    = (float*) (wsb + 20727808);     // 6,400,000
  float*  readout= (float*) (wsb + 27127808);     // 23,040
  float*  cnt    = (float*) (wsb + 27150848);     // 256

  hipMemsetAsync(readout, 0, 23040 + 256, stream);
  edge_mlp_pack_kernel<<<NEP2 / 64, 256, 0, stream>>>(ea, We1, be1, Upkt);
  bpk_pack_kernel<<<(NCH * 8 * 4 * 64) / 256, 256, 0, stream>>>(We2, be2, Bpk);
  node_in_kernel<<<(NN * 64 + 255) / 256, 256, 0, stream>>>(x, W_in, b_in, h);

  for (int it = 0; it < NUM_ITER; ++it) {
    hipMemsetAsync(agg, 0, (size_t)NN * 64 * sizeof(float), stream);
    edge_rgemm_kernel<<<NBLK, 512, 0, stream>>>(Upkt, Bpk, h, srcp, dstp, agg);
    node_update_kernel<<<(NN + NPB - 1) / NPB, 256, 0, stream>>>(
        h, agg, W_root, b_conv, W_ih, b_ih, W_hh, b_hh);
  }

  head_kernel<<<NN, 64, 0, stream>>>(h, x, batch, Wo1, bo1, Wo2, bo2, feat, readout, cnt);
  ratio_kernel<<<1, 64, 0, stream>>>(readout, cnt, Wp, bp, ratio);
}

// Round 5
// 820.573 us; speedup vs baseline: 5.0389x; 1.0512x over previous
//
#include <hip/hip_runtime.h>
#include <math.h>

#define NN 25000
#define NE 50000
#define NEP2 50176            // 196 * 256 edges (padded)
#define NBLK 196
#define NATOM 26
#define NUM_ITER 3
#define NCH 33                // K' = 33 chunks x 256 (4 k-values x 64 i's)
#define NPB 32

typedef __attribute__((ext_vector_type(8))) short bf16x8;
typedef __attribute__((ext_vector_type(8))) unsigned short ushort8_t;
typedef __attribute__((ext_vector_type(4))) float f32x4;

static __device__ __forceinline__ ushort f2bf(float f) {
  unsigned u = __float_as_uint(f);
  unsigned r = (u + 0x7FFFu + ((u >> 16) & 1u)) >> 16;
  return (ushort)r;
}
static __device__ __forceinline__ unsigned cvt_pk_bf16(float a, float b) {
  unsigned r;
  asm("v_cvt_pk_bf16_f32 %0, %1, %2" : "=v"(r) : "v"(a), "v"(b));
  return r;
}
static __device__ __forceinline__ float bflo(unsigned u) { return __uint_as_float(u << 16); }
static __device__ __forceinline__ float bfhi(unsigned u) { return __uint_as_float(u & 0xFFFF0000u); }

// ---------------- U pack: relu(ea@We1+be1) -> Upkt[g][e][4] bf16 (k-group-major)
__global__ __launch_bounds__(256) void edge_mlp_pack_kernel(
    const float* __restrict__ ea, const float* __restrict__ We1,
    const float* __restrict__ be1, ushort* __restrict__ Upkt) {
  int t = threadIdx.x;
  int el = t & 63, seg = t >> 6;
  int e = blockIdx.x * 64 + el;       // grid 784 -> e < 50176
  bool valid = (e < NE);
  float a0 = 0.f, a1 = 0.f, a2 = 0.f, a3 = 0.f;
  if (valid) { a0 = ea[e * 4]; a1 = ea[e * 4 + 1]; a2 = ea[e * 4 + 2]; a3 = ea[e * 4 + 3]; }
  #pragma unroll
  for (int q = 0; q < 8; ++q) {
    int g = seg * 8 + q;              // k-group 0..31 (k = 4g..4g+3 < 128)
    ushort out[4];
    #pragma unroll
    for (int kk = 0; kk < 4; ++kk) {
      int k = g * 4 + kk;
      float v = be1[k];
      v = fmaf(a0, We1[k], v);
      v = fmaf(a1, We1[128 + k], v);
      v = fmaf(a2, We1[256 + k], v);
      v = fmaf(a3, We1[384 + k], v);
      out[kk] = valid ? f2bf(fmaxf(v, 0.f)) : (ushort)0;
    }
    *(ushort4*)&Upkt[((size_t)g * NEP2 + e) * 4] = *(ushort4*)out;
  }
  if (seg == 0) {                     // g=32: k=128 -> 1.0 (be2 fold), 129..131 -> 0
    ushort out[4] = {(ushort)(valid ? 0x3F80 : 0), 0, 0, 0};
    *(ushort4*)&Upkt[((size_t)32 * NEP2 + e) * 4] = *(ushort4*)out;
  }
}

// ---------------- B pack: We2ext[f][o] -> per-lane fragment order
// Bpk[((c*8+ks)*4+nt)*64 + lane][8]; elem j at f = c*256+ks*32+kl(lg,j), o = nt*16+l15
__global__ __launch_bounds__(256) void bpk_pack_kernel(
    const float* __restrict__ We2, const float* __restrict__ be2,
    ushort* __restrict__ Bpk) {
  int idx = blockIdx.x * 256 + threadIdx.x;   // 264 blocks -> 67584 = 33*8*4*64
  int lane = idx & 63;
  int nt = (idx >> 6) & 3;
  int ks = (idx >> 8) & 7;
  int c = idx >> 11;
  int l15 = lane & 15, lg = lane >> 4;
  int o = nt * 16 + l15;
  ushort v[8];
  #pragma unroll
  for (int j = 0; j < 8; ++j) {
    int kl = (j < 4) ? (4 * lg + j) : (12 + 4 * lg + j);   // split-halves k-map
    int f = c * 256 + ks * 32 + kl;
    int k = f >> 6, i = f & 63;
    float wv = 0.f;
    if (k < 128) wv = We2[(size_t)k * 4096 + i * 64 + o];
    else if (k == 128) wv = be2[i * 64 + o];
    v[j] = f2bf(wv);
  }
  *(ushort8_t*)(Bpk + (size_t)idx * 8) = *(ushort8_t*)v;
}

// ---------------- fused edge-message GEMM: msg = (U (x) s) @ We2flat, + scatter
// 512 threads = 8 waves; wave tile = 32 edge-rows (mt=0..1), full N=64 (nt=0..3).
__global__ __launch_bounds__(512, 1) void edge_rgemm_kernel(
    const ushort* __restrict__ Upkt, const ushort* __restrict__ Bpk,
    const float* __restrict__ hv, const int* __restrict__ src,
    const int* __restrict__ dst, float* __restrict__ agg) {
  __shared__ ushort sB[2][16384];   // 2 x 32KB frag-packed B chunk (2048 frags x 8)
  __shared__ ushort sU[2][1024];    // 2 x 2KB U chunk [256 e][4 k]
  __shared__ ushort sS[256][72];    // s bf16, padded row
  int tid = threadIdx.x;            // 0..511
  int lane = tid & 63, w = tid >> 6;
  int l15 = lane & 15, lg = lane >> 4;
  int e0 = blockIdx.x * 256;

  // stage s = bf16(h[src[e]])
  #pragma unroll
  for (int r = 0; r < 8; ++r) {
    int idx = r * 512 + tid;        // 0..4095 = 256 rows x 16 float4-parts
    int el = idx >> 4, part = idx & 15;
    int e = e0 + el;
    float4 v = make_float4(0.f, 0.f, 0.f, 0.f);
    if (e < NE) v = ((const float4*)hv)[(size_t)src[e] * 16 + part];
    unsigned lo = cvt_pk_bf16(v.x, v.y);
    unsigned hi = cvt_pk_bf16(v.z, v.w);
    *(uint2*)&sS[el][part * 4] = make_uint2(lo, hi);
  }

  // prologue: stage chunk 0 (ALL 2048 fragments: 512 threads x 4)
  ushort8_t rB[4]; uint2 rU;
  #pragma unroll
  for (int r = 0; r < 4; ++r)
    rB[r] = *(const ushort8_t*)(Bpk + ((size_t)r * 512 + tid) * 8);
  if (tid < 256) rU = *(const uint2*)(Upkt + (size_t)e0 * 4 + tid * 4);
  #pragma unroll
  for (int r = 0; r < 4; ++r)
    *(ushort8_t*)&sB[0][((size_t)r * 512 + tid) * 8] = rB[r];
  if (tid < 256) *(uint2*)&sU[0][tid * 4] = rU;
  __syncthreads();

  // per-wave s fragments: row = w*32 + mt*16 + l15, i = p*32 + g*16 + 4*lg
  float4 sreg[2][2][2];
  #pragma unroll
  for (int mt = 0; mt < 2; ++mt)
    #pragma unroll
    for (int p = 0; p < 2; ++p)
      #pragma unroll
      for (int g = 0; g < 2; ++g) {
        uint2 d = *(const uint2*)&sS[w * 32 + mt * 16 + l15][p * 32 + g * 16 + 4 * lg];
        sreg[mt][p][g] = make_float4(bflo(d.x), bfhi(d.x), bflo(d.y), bfhi(d.y));
      }

  f32x4 acc[2][4];
  #pragma unroll
  for (int mt = 0; mt < 2; ++mt)
    #pragma unroll
    for (int nt = 0; nt < 4; ++nt) acc[mt][nt] = (f32x4){0.f, 0.f, 0.f, 0.f};

  for (int c = 0; c < NCH; ++c) {
    int cur = c & 1;
    bool more = (c + 1 < NCH);
    if (more) {  // T14: issue next-chunk loads early
      const ushort* bs = Bpk + (size_t)(c + 1) * 16384;
      #pragma unroll
      for (int r = 0; r < 4; ++r)
        rB[r] = *(const ushort8_t*)(bs + ((size_t)r * 512 + tid) * 8);
      if (tid < 256)
        rU = *(const uint2*)(Upkt + ((size_t)(c + 1) * NEP2 + e0) * 4 + tid * 4);
    }
    float uu[2][4];
    #pragma unroll
    for (int mt = 0; mt < 2; ++mt) {
      uint2 d = *(const uint2*)&sU[cur][(w * 32 + mt * 16 + l15) * 4];
      uu[mt][0] = bflo(d.x); uu[mt][1] = bfhi(d.x);
      uu[mt][2] = bflo(d.y); uu[mt][3] = bfhi(d.y);
    }
    #pragma unroll
    for (int ks = 0; ks < 8; ++ks) {
      int p = ks & 1, ku = ks >> 1;
      bf16x8 bfr[4];
      #pragma unroll
      for (int nt = 0; nt < 4; ++nt)
        bfr[nt] = *(const bf16x8*)&sB[cur][(((size_t)ks * 4 + nt) * 64 + lane) * 8];
      #pragma unroll
      for (int mt = 0; mt < 2; ++mt) {
        float u = uu[mt][ku];
        float4 s0 = sreg[mt][p][0], s1 = sreg[mt][p][1];
        union { bf16x8 v; unsigned u32[4]; } af;
        af.u32[0] = cvt_pk_bf16(s0.x * u, s0.y * u);
        af.u32[1] = cvt_pk_bf16(s0.z * u, s0.w * u);
        af.u32[2] = cvt_pk_bf16(s1.x * u, s1.y * u);
        af.u32[3] = cvt_pk_bf16(s1.z * u, s1.w * u);
        #pragma unroll
        for (int nt = 0; nt < 4; ++nt)
          acc[mt][nt] = __builtin_amdgcn_mfma_f32_16x16x32_bf16(af.v, bfr[nt], acc[mt][nt], 0, 0, 0);
      }
    }
    if (more) {  // write-late into the other buffer
      int nb = cur ^ 1;
      #pragma unroll
      for (int r = 0; r < 4; ++r)
        *(ushort8_t*)&sB[nb][((size_t)r * 512 + tid) * 8] = rB[r];
      if (tid < 256) *(uint2*)&sU[nb][tid * 4] = rU;
    }
    __syncthreads();
  }

  // scatter: D row (within 16-tile) = lg*4 + rr, col = nt*16 + l15
  #pragma unroll
  for (int mt = 0; mt < 2; ++mt) {
    #pragma unroll
    for (int rr = 0; rr < 4; ++rr) {
      int e = e0 + w * 32 + mt * 16 + lg * 4 + rr;
      if (e < NE) {
        int d = dst[e];
        #pragma unroll
        for (int nt = 0; nt < 4; ++nt)
          atomicAdd(&agg[(size_t)d * 64 + nt * 16 + l15], acc[mt][nt][rr]);
      }
    }
  }
}

// ---------------- node input transform
__global__ __launch_bounds__(256) void node_in_kernel(
    const float* __restrict__ x, const float* __restrict__ W_in,
    const float* __restrict__ b_in, float* __restrict__ h) {
  int idx = blockIdx.x * 256 + threadIdx.x;
  if (idx >= NN * 64) return;
  int n = idx >> 6, c = idx & 63;
  float acc = b_in[c];
  #pragma unroll
  for (int j = 0; j < NATOM; ++j) acc = fmaf(x[n * NATOM + j], W_in[j * 64 + c], acc);
  h[idx] = fmaxf(acc, 0.f);
}

// ---------------- m = relu(h@W_root + agg + b_conv); GRU -> h (in place)
__global__ __launch_bounds__(256) void node_update_kernel(
    float* __restrict__ hv, const float* __restrict__ agg,
    const float* __restrict__ W_root, const float* __restrict__ b_conv,
    const float* __restrict__ W_ih, const float* __restrict__ b_ih,
    const float* __restrict__ W_hh, const float* __restrict__ b_hh) {
  __shared__ float wroot[64 * 64];
  __shared__ float wihT[64 * 193];
  __shared__ float whhT[64 * 193];
  __shared__ float s_row[NPB * 64];
  __shared__ float s_m[NPB * 64];
  int tid = threadIdx.x;
  int n0 = blockIdx.x * NPB;

  for (int idx = tid; idx < 64 * 16; idx += 256)
    ((float4*)wroot)[idx] = ((const float4*)W_root)[idx];
  for (int idx4 = tid; idx4 < 192 * 16; idx4 += 256) {
    int j = idx4 >> 4, i4 = (idx4 & 15) * 4;
    float4 a = ((const float4*)W_ih)[idx4];
    float4 b = ((const float4*)W_hh)[idx4];
    wihT[(i4 + 0) * 193 + j] = a.x; wihT[(i4 + 1) * 193 + j] = a.y;
    wihT[(i4 + 2) * 193 + j] = a.z; wihT[(i4 + 3) * 193 + j] = a.w;
    whhT[(i4 + 0) * 193 + j] = b.x; whhT[(i4 + 1) * 193 + j] = b.y;
    whhT[(i4 + 2) * 193 + j] = b.z; whhT[(i4 + 3) * 193 + j] = b.w;
  }
  for (int idx = tid; idx < NPB * 64; idx += 256) {
    int n = n0 + (idx >> 6);
    s_row[idx] = (n < NN) ? hv[(size_t)n * 64 + (idx & 63)] : 0.f;
  }
  __syncthreads();

  int c = tid & 63, g = tid >> 6;
  #pragma unroll
  for (int q = 0; q < 8; ++q) {
    int nl = g + 4 * q;
    int n = n0 + nl;
    float a = 0.f;
    for (int i = 0; i < 64; ++i) a = fmaf(s_row[nl * 64 + i], wroot[i * 64 + c], a);
    float val = 0.f;
    if (n < NN) val = fmaxf(a + agg[(size_t)n * 64 + c] + b_conv[c], 0.f);
    s_m[nl * 64 + c] = val;
  }
  __syncthreads();
  #pragma unroll
  for (int q = 0; q < 8; ++q) {
    int nl = g + 4 * q;
    int n = n0 + nl;
    if (n >= NN) continue;
    float gir = b_ih[c], giz = b_ih[64 + c], gin = b_ih[128 + c];
    float ghr = b_hh[c], ghz = b_hh[64 + c], ghn = b_hh[128 + c];
    for (int i = 0; i < 64; ++i) {
      float mv = s_m[nl * 64 + i];
      float hh = s_row[nl * 64 + i];
      gir = fmaf(mv, wihT[i * 193 + c], gir);
      giz = fmaf(mv, wihT[i * 193 + 64 + c], giz);
      gin = fmaf(mv, wihT[i * 193 + 128 + c], gin);
      ghr = fmaf(hh, whhT[i * 193 + c], ghr);
      ghz = fmaf(hh, whhT[i * 193 + 64 + c], ghz);
      ghn = fmaf(hh, whhT[i * 193 + 128 + c], ghn);
    }
    float r = 1.f / (1.f + __expf(-(gir + ghr)));
    float z = 1.f / (1.f + __expf(-(giz + ghz)));
    float nnv = tanhf(fmaf(r, ghn, gin));
    float hprev = s_row[nl * 64 + c];
    hv[(size_t)n * 64 + c] = (1.f - z) * nnv + z * hprev;
  }
}

// ---------------- head v2: 32 nodes/block, weights in LDS, wave-reduce norm
__global__ __launch_bounds__(256) void head2_kernel(
    const float* __restrict__ hv, const float* __restrict__ x,
    const int* __restrict__ batch,
    const float* __restrict__ Wo1, const float* __restrict__ bo1,
    const float* __restrict__ Wo2, const float* __restrict__ bo2,
    float* __restrict__ feat, float* __restrict__ readout, float* __restrict__ cnt) {
  __shared__ float wo1[64 * 64];     // 16 KB  [i][c]
  __shared__ float wo2[64 * 64];     // 16 KB  [i][c]
  __shared__ float s_row[NPB * 64];  // 8 KB
  __shared__ float s_o1[NPB * 64];   // 8 KB
  int tid = threadIdx.x;
  int n0 = blockIdx.x * NPB;

  for (int idx = tid; idx < 64 * 16; idx += 256) {
    ((float4*)wo1)[idx] = ((const float4*)Wo1)[idx];
    ((float4*)wo2)[idx] = ((const float4*)Wo2)[idx];
  }
  for (int idx = tid; idx < NPB * 64; idx += 256) {
    int n = n0 + (idx >> 6);
    s_row[idx] = (n < NN) ? hv[(size_t)n * 64 + (idx & 63)] : 0.f;
  }
  __syncthreads();

  int c = tid & 63, g = tid >> 6;
  // phase 1: o1 = relu(h@Wo1 + bo1)
  #pragma unroll
  for (int q = 0; q < 8; ++q) {
    int nl = g + 4 * q;
    float a = bo1[c];
    for (int i = 0; i < 64; ++i) a = fmaf(s_row[nl * 64 + i], wo1[i * 64 + c], a);
    s_o1[nl * 64 + c] = fmaxf(a, 0.f);
  }
  __syncthreads();
  // phase 2: o = o1@Wo2 + bo2; norm over [o, x]; feat + readout
  #pragma unroll
  for (int q = 0; q < 8; ++q) {
    int nl = g + 4 * q;              // all 64 lanes of this wave share node nl
    int n = n0 + nl;
    float b = bo2[c];
    for (int i = 0; i < 64; ++i) b = fmaf(s_o1[nl * 64 + i], wo2[i * 64 + c], b);
    float xv = (c < NATOM && n < NN) ? x[(size_t)n * NATOM + c] : 0.f;
    float sq = b * b + xv * xv;
    #pragma unroll
    for (int off = 1; off < 64; off <<= 1) sq += __shfl_xor(sq, off);
    if (n >= NN) continue;
    float inv = 1.f / fmaxf(sqrtf(sq), 1e-12f);
    int bg = batch[n];
    float fo = b * inv;
    feat[(size_t)n * 90 + c] = fo;
    atomicAdd(&readout[bg * 90 + c], fo);
    if (c < NATOM) {
      float fx = xv * inv;
      feat[(size_t)n * 90 + 64 + c] = fx;
      atomicAdd(&readout[bg * 90 + 64 + c], fx);
    }
    if (c == 0) atomicAdd(&cnt[bg], 1.f);
  }
}

__global__ __launch_bounds__(64) void ratio_kernel(
    const float* __restrict__ readout, const float* __restrict__ cnt,
    const float* __restrict__ Wp, const float* __restrict__ bp,
    float* __restrict__ ratio) {
  int g = threadIdx.x;
  float c = fmaxf(cnt[g], 1.f);
  float a = bp[0];
  for (int j = 0; j < 90; ++j) a = fmaf(readout[g * 90 + j] / c, Wp[j], a);
  ratio[g] = 1.f / (1.f + __expf(-a));
}

// ==================== launcher ====================

extern "C" void kernel_launch(void* const* d_in, const int* in_sizes, int n_in,
                              void* d_out, int out_size, void* d_ws, size_t ws_size,
                              hipStream_t stream) {
  const float* x      = (const float*)d_in[0];
  const int*   ei     = (const int*)  d_in[1];
  const float* ea     = (const float*)d_in[2];
  const int*   batch  = (const int*)  d_in[3];
  const float* W_in   = (const float*)d_in[4];
  const float* b_in   = (const float*)d_in[5];
  const float* We1    = (const float*)d_in[6];
  const float* be1    = (const float*)d_in[7];
  const float* We2    = (const float*)d_in[8];
  const float* be2    = (const float*)d_in[9];
  const float* W_root = (const float*)d_in[10];
  const float* b_conv = (const float*)d_in[11];
  const float* W_ih   = (const float*)d_in[12];
  const float* b_ih   = (const float*)d_in[13];
  const float* W_hh   = (const float*)d_in[14];
  const float* b_hh   = (const float*)d_in[15];
  const float* Wo1    = (const float*)d_in[16];
  const float* bo1    = (const float*)d_in[17];
  const float* Wo2    = (const float*)d_in[18];
  const float* bo2    = (const float*)d_in[19];
  const float* Wp     = (const float*)d_in[20];
  const float* bp     = (const float*)d_in[21];

  const int* srcp = ei;
  const int* dstp = ei + NE;
  float* feat  = (float*)d_out;
  float* ratio = feat + (size_t)NN * 90;

  // ws layout (bytes): total ~27.2 MB (round-1 proved >= 39.3 MB available)
  char* wsb = (char*)d_ws;
  ushort* Upkt   = (ushort*)(wsb + 0);            // 33*50176*4*2  = 13,246,464
  ushort* Bpk    = (ushort*)(wsb + 13246464);     // 33*8*4*64*8*2 =  1,081,344
  float*  h      = (float*) (wsb + 14327808);     // 6,400,000
  float*  agg    = (float*) (wsb + 20727808);     // 6,400,000
  float*  readout= (float*) (wsb + 27127808);     // 23,040
  float*  cnt    = (float*) (wsb + 27150848);     // 256

  hipMemsetAsync(readout, 0, 23040 + 256, stream);
  edge_mlp_pack_kernel<<<NEP2 / 64, 256, 0, stream>>>(ea, We1, be1, Upkt);
  bpk_pack_kernel<<<(NCH * 8 * 4 * 64) / 256, 256, 0, stream>>>(We2, be2, Bpk);
  node_in_kernel<<<(NN * 64 + 255) / 256, 256, 0, stream>>>(x, W_in, b_in, h);

  for (int it = 0; it < NUM_ITER; ++it) {
    hipMemsetAsync(agg, 0, (size_t)NN * 64 * sizeof(float), stream);
    edge_rgemm_kernel<<<NBLK, 512, 0, stream>>>(Upkt, Bpk, h, srcp, dstp, agg);
    node_update_kernel<<<(NN + NPB - 1) / NPB, 256, 0, stream>>>(
        h, agg, W_root, b_conv, W_ih, b_ih, W_hh, b_hh);
  }

  head2_kernel<<<(NN + NPB - 1) / NPB, 256, 0, stream>>>(
      h, x, batch, Wo1, bo1, Wo2, bo2, feat, readout, cnt);
  ratio_kernel<<<1, 64, 0, stream>>>(readout, cnt, Wp, bp, ratio);
}

// Round 6
// 703.185 us; speedup vs baseline: 5.8801x; 1.1669x over previous
//
#include <hip/hip_runtime.h>
#include <math.h>

#define NN 25000
#define NE 50000
#define NEP2 50176            // 196 * 256 edges (padded)
#define NBLK 196
#define NATOM 26
#define NUM_ITER 3
#define NCH 33                // K' = 33 chunks x 256 (4 k-values x 64 i's)
#define NPB 32

typedef __attribute__((ext_vector_type(8))) short bf16x8;
typedef __attribute__((ext_vector_type(8))) unsigned short ushort8_t;
typedef __attribute__((ext_vector_type(4))) float f32x4;

static __device__ __forceinline__ ushort f2bf(float f) {
  unsigned u = __float_as_uint(f);
  unsigned r = (u + 0x7FFFu + ((u >> 16) & 1u)) >> 16;
  return (ushort)r;
}
static __device__ __forceinline__ unsigned cvt_pk_bf16(float a, float b) {
  unsigned r;
  asm("v_cvt_pk_bf16_f32 %0, %1, %2" : "=v"(r) : "v"(a), "v"(b));
  return r;
}
static __device__ __forceinline__ float bflo(unsigned u) { return __uint_as_float(u << 16); }
static __device__ __forceinline__ float bfhi(unsigned u) { return __uint_as_float(u & 0xFFFF0000u); }

// ---------------- U pack: relu(ea@We1+be1) -> Upkt[g][e][4] bf16 (k-group-major)
__global__ __launch_bounds__(256) void edge_mlp_pack_kernel(
    const float* __restrict__ ea, const float* __restrict__ We1,
    const float* __restrict__ be1, ushort* __restrict__ Upkt) {
  int t = threadIdx.x;
  int el = t & 63, seg = t >> 6;
  int e = blockIdx.x * 64 + el;       // grid 784 -> e < 50176
  bool valid = (e < NE);
  float a0 = 0.f, a1 = 0.f, a2 = 0.f, a3 = 0.f;
  if (valid) { a0 = ea[e * 4]; a1 = ea[e * 4 + 1]; a2 = ea[e * 4 + 2]; a3 = ea[e * 4 + 3]; }
  #pragma unroll
  for (int q = 0; q < 8; ++q) {
    int g = seg * 8 + q;              // k-group 0..31 (k = 4g..4g+3 < 128)
    ushort out[4];
    #pragma unroll
    for (int kk = 0; kk < 4; ++kk) {
      int k = g * 4 + kk;
      float v = be1[k];
      v = fmaf(a0, We1[k], v);
      v = fmaf(a1, We1[128 + k], v);
      v = fmaf(a2, We1[256 + k], v);
      v = fmaf(a3, We1[384 + k], v);
      out[kk] = valid ? f2bf(fmaxf(v, 0.f)) : (ushort)0;
    }
    *(ushort4*)&Upkt[((size_t)g * NEP2 + e) * 4] = *(ushort4*)out;
  }
  if (seg == 0) {                     // g=32: k=128 -> 1.0 (be2 fold), 129..131 -> 0
    ushort out[4] = {(ushort)(valid ? 0x3F80 : 0), 0, 0, 0};
    *(ushort4*)&Upkt[((size_t)32 * NEP2 + e) * 4] = *(ushort4*)out;
  }
}

// ---------------- B pack: We2ext[f][o] -> per-lane fragment order
// Bpk[((c*8+ks)*4+nt)*64 + lane][8]; elem j at f = c*256+ks*32+kl(lg,j), o = nt*16+l15
__global__ __launch_bounds__(256) void bpk_pack_kernel(
    const float* __restrict__ We2, const float* __restrict__ be2,
    ushort* __restrict__ Bpk) {
  int idx = blockIdx.x * 256 + threadIdx.x;   // 264 blocks -> 67584 = 33*8*4*64
  int lane = idx & 63;
  int nt = (idx >> 6) & 3;
  int ks = (idx >> 8) & 7;
  int c = idx >> 11;
  int l15 = lane & 15, lg = lane >> 4;
  int o = nt * 16 + l15;
  ushort v[8];
  #pragma unroll
  for (int j = 0; j < 8; ++j) {
    int kl = (j < 4) ? (4 * lg + j) : (12 + 4 * lg + j);   // split-halves k-map
    int f = c * 256 + ks * 32 + kl;
    int k = f >> 6, i = f & 63;
    float wv = 0.f;
    if (k < 128) wv = We2[(size_t)k * 4096 + i * 64 + o];
    else if (k == 128) wv = be2[i * 64 + o];
    v[j] = f2bf(wv);
  }
  *(ushort8_t*)(Bpk + (size_t)idx * 8) = *(ushort8_t*)v;
}

// ---------------- fused edge-message GEMM: msg = (U (x) s) @ We2flat, + scatter
// 512 threads = 8 waves; wave tile = 32 edge-rows (mt=0..1), full N=64 (nt=0..3).
__global__ __launch_bounds__(512, 1) void edge_rgemm_kernel(
    const ushort* __restrict__ Upkt, const ushort* __restrict__ Bpk,
    const float* __restrict__ hv, const int* __restrict__ src,
    const int* __restrict__ dst, float* __restrict__ agg) {
  __shared__ ushort sB[2][16384];   // 2 x 32KB frag-packed B chunk (2048 frags x 8)
  __shared__ ushort sU[2][1024];    // 2 x 2KB U chunk [256 e][4 k]
  __shared__ ushort sS[256][72];    // s bf16, padded row
  int tid = threadIdx.x;            // 0..511
  int lane = tid & 63, w = tid >> 6;
  int l15 = lane & 15, lg = lane >> 4;
  int e0 = blockIdx.x * 256;

  // stage s = bf16(h[src[e]])
  #pragma unroll
  for (int r = 0; r < 8; ++r) {
    int idx = r * 512 + tid;        // 0..4095 = 256 rows x 16 float4-parts
    int el = idx >> 4, part = idx & 15;
    int e = e0 + el;
    float4 v = make_float4(0.f, 0.f, 0.f, 0.f);
    if (e < NE) v = ((const float4*)hv)[(size_t)src[e] * 16 + part];
    unsigned lo = cvt_pk_bf16(v.x, v.y);
    unsigned hi = cvt_pk_bf16(v.z, v.w);
    *(uint2*)&sS[el][part * 4] = make_uint2(lo, hi);
  }

  // prologue: stage chunk 0 (ALL 2048 fragments: 512 threads x 4)
  ushort8_t rB[4]; uint2 rU;
  #pragma unroll
  for (int r = 0; r < 4; ++r)
    rB[r] = *(const ushort8_t*)(Bpk + ((size_t)r * 512 + tid) * 8);
  if (tid < 256) rU = *(const uint2*)(Upkt + (size_t)e0 * 4 + tid * 4);
  #pragma unroll
  for (int r = 0; r < 4; ++r)
    *(ushort8_t*)&sB[0][((size_t)r * 512 + tid) * 8] = rB[r];
  if (tid < 256) *(uint2*)&sU[0][tid * 4] = rU;
  __syncthreads();

  // per-wave s fragments: row = w*32 + mt*16 + l15, i = p*32 + g*16 + 4*lg
  float4 sreg[2][2][2];
  #pragma unroll
  for (int mt = 0; mt < 2; ++mt)
    #pragma unroll
    for (int p = 0; p < 2; ++p)
      #pragma unroll
      for (int g = 0; g < 2; ++g) {
        uint2 d = *(const uint2*)&sS[w * 32 + mt * 16 + l15][p * 32 + g * 16 + 4 * lg];
        sreg[mt][p][g] = make_float4(bflo(d.x), bfhi(d.x), bflo(d.y), bfhi(d.y));
      }

  f32x4 acc[2][4];
  #pragma unroll
  for (int mt = 0; mt < 2; ++mt)
    #pragma unroll
    for (int nt = 0; nt < 4; ++nt) acc[mt][nt] = (f32x4){0.f, 0.f, 0.f, 0.f};

  for (int c = 0; c < NCH; ++c) {
    int cur = c & 1;
    bool more = (c + 1 < NCH);
    if (more) {  // T14: issue next-chunk loads early
      const ushort* bs = Bpk + (size_t)(c + 1) * 16384;
      #pragma unroll
      for (int r = 0; r < 4; ++r)
        rB[r] = *(const ushort8_t*)(bs + ((size_t)r * 512 + tid) * 8);
      if (tid < 256)
        rU = *(const uint2*)(Upkt + ((size_t)(c + 1) * NEP2 + e0) * 4 + tid * 4);
    }
    float uu[2][4];
    #pragma unroll
    for (int mt = 0; mt < 2; ++mt) {
      uint2 d = *(const uint2*)&sU[cur][(w * 32 + mt * 16 + l15) * 4];
      uu[mt][0] = bflo(d.x); uu[mt][1] = bfhi(d.x);
      uu[mt][2] = bflo(d.y); uu[mt][3] = bfhi(d.y);
    }
    #pragma unroll
    for (int ks = 0; ks < 8; ++ks) {
      int p = ks & 1, ku = ks >> 1;
      bf16x8 bfr[4];
      #pragma unroll
      for (int nt = 0; nt < 4; ++nt)
        bfr[nt] = *(const bf16x8*)&sB[cur][(((size_t)ks * 4 + nt) * 64 + lane) * 8];
      #pragma unroll
      for (int mt = 0; mt < 2; ++mt) {
        float u = uu[mt][ku];
        float4 s0 = sreg[mt][p][0], s1 = sreg[mt][p][1];
        union { bf16x8 v; unsigned u32[4]; } af;
        af.u32[0] = cvt_pk_bf16(s0.x * u, s0.y * u);
        af.u32[1] = cvt_pk_bf16(s0.z * u, s0.w * u);
        af.u32[2] = cvt_pk_bf16(s1.x * u, s1.y * u);
        af.u32[3] = cvt_pk_bf16(s1.z * u, s1.w * u);
        #pragma unroll
        for (int nt = 0; nt < 4; ++nt)
          acc[mt][nt] = __builtin_amdgcn_mfma_f32_16x16x32_bf16(af.v, bfr[nt], acc[mt][nt], 0, 0, 0);
      }
    }
    if (more) {  // write-late into the other buffer
      int nb = cur ^ 1;
      #pragma unroll
      for (int r = 0; r < 4; ++r)
        *(ushort8_t*)&sB[nb][((size_t)r * 512 + tid) * 8] = rB[r];
      if (tid < 256) *(uint2*)&sU[nb][tid * 4] = rU;
    }
    __syncthreads();
  }

  // scatter: D row (within 16-tile) = lg*4 + rr, col = nt*16 + l15
  #pragma unroll
  for (int mt = 0; mt < 2; ++mt) {
    #pragma unroll
    for (int rr = 0; rr < 4; ++rr) {
      int e = e0 + w * 32 + mt * 16 + lg * 4 + rr;
      if (e < NE) {
        int d = dst[e];
        #pragma unroll
        for (int nt = 0; nt < 4; ++nt)
          atomicAdd(&agg[(size_t)d * 64 + nt * 16 + l15], acc[mt][nt][rr]);
      }
    }
  }
}

// ---------------- node input transform
__global__ __launch_bounds__(256) void node_in_kernel(
    const float* __restrict__ x, const float* __restrict__ W_in,
    const float* __restrict__ b_in, float* __restrict__ h) {
  int idx = blockIdx.x * 256 + threadIdx.x;
  if (idx >= NN * 64) return;
  int n = idx >> 6, c = idx & 63;
  float acc = b_in[c];
  #pragma unroll
  for (int j = 0; j < NATOM; ++j) acc = fmaf(x[n * NATOM + j], W_in[j * 64 + c], acc);
  h[idx] = fmaxf(acc, 0.f);
}

// ---------------- m = relu(h@W_root + agg + b_conv); GRU -> h (in place)
__global__ __launch_bounds__(256) void node_update_kernel(
    float* __restrict__ hv, const float* __restrict__ agg,
    const float* __restrict__ W_root, const float* __restrict__ b_conv,
    const float* __restrict__ W_ih, const float* __restrict__ b_ih,
    const float* __restrict__ W_hh, const float* __restrict__ b_hh) {
  __shared__ float wroot[64 * 64];
  __shared__ float wihT[64 * 193];
  __shared__ float whhT[64 * 193];
  __shared__ float s_row[NPB * 64];
  __shared__ float s_m[NPB * 64];
  int tid = threadIdx.x;
  int n0 = blockIdx.x * NPB;

  for (int idx = tid; idx < 64 * 16; idx += 256)
    ((float4*)wroot)[idx] = ((const float4*)W_root)[idx];
  for (int idx4 = tid; idx4 < 192 * 16; idx4 += 256) {
    int j = idx4 >> 4, i4 = (idx4 & 15) * 4;
    float4 a = ((const float4*)W_ih)[idx4];
    float4 b = ((const float4*)W_hh)[idx4];
    wihT[(i4 + 0) * 193 + j] = a.x; wihT[(i4 + 1) * 193 + j] = a.y;
    wihT[(i4 + 2) * 193 + j] = a.z; wihT[(i4 + 3) * 193 + j] = a.w;
    whhT[(i4 + 0) * 193 + j] = b.x; whhT[(i4 + 1) * 193 + j] = b.y;
    whhT[(i4 + 2) * 193 + j] = b.z; whhT[(i4 + 3) * 193 + j] = b.w;
  }
  for (int idx = tid; idx < NPB * 64; idx += 256) {
    int n = n0 + (idx >> 6);
    s_row[idx] = (n < NN) ? hv[(size_t)n * 64 + (idx & 63)] : 0.f;
  }
  __syncthreads();

  int c = tid & 63, g = tid >> 6;
  #pragma unroll
  for (int q = 0; q < 8; ++q) {
    int nl = g + 4 * q;
    int n = n0 + nl;
    float a = 0.f;
    for (int i = 0; i < 64; ++i) a = fmaf(s_row[nl * 64 + i], wroot[i * 64 + c], a);
    float val = 0.f;
    if (n < NN) val = fmaxf(a + agg[(size_t)n * 64 + c] + b_conv[c], 0.f);
    s_m[nl * 64 + c] = val;
  }
  __syncthreads();
  #pragma unroll
  for (int q = 0; q < 8; ++q) {
    int nl = g + 4 * q;
    int n = n0 + nl;
    if (n >= NN) continue;
    float gir = b_ih[c], giz = b_ih[64 + c], gin = b_ih[128 + c];
    float ghr = b_hh[c], ghz = b_hh[64 + c], ghn = b_hh[128 + c];
    for (int i = 0; i < 64; ++i) {
      float mv = s_m[nl * 64 + i];
      float hh = s_row[nl * 64 + i];
      gir = fmaf(mv, wihT[i * 193 + c], gir);
      giz = fmaf(mv, wihT[i * 193 + 64 + c], giz);
      gin = fmaf(mv, wihT[i * 193 + 128 + c], gin);
      ghr = fmaf(hh, whhT[i * 193 + c], ghr);
      ghz = fmaf(hh, whhT[i * 193 + 64 + c], ghz);
      ghn = fmaf(hh, whhT[i * 193 + 128 + c], ghn);
    }
    float r = 1.f / (1.f + __expf(-(gir + ghr)));
    float z = 1.f / (1.f + __expf(-(giz + ghz)));
    float nnv = tanhf(fmaf(r, ghn, gin));
    float hprev = s_row[nl * 64 + c];
    hv[(size_t)n * 64 + c] = (1.f - z) * nnv + z * hprev;
  }
}

// ---------------- head v3: feat only (NO atomics)
__global__ __launch_bounds__(256) void head2_kernel(
    const float* __restrict__ hv, const float* __restrict__ x,
    const float* __restrict__ Wo1, const float* __restrict__ bo1,
    const float* __restrict__ Wo2, const float* __restrict__ bo2,
    float* __restrict__ feat) {
  __shared__ float wo1[64 * 64];     // 16 KB  [i][c]
  __shared__ float wo2[64 * 64];     // 16 KB  [i][c]
  __shared__ float s_row[NPB * 64];  // 8 KB
  __shared__ float s_o1[NPB * 64];   // 8 KB
  int tid = threadIdx.x;
  int n0 = blockIdx.x * NPB;

  for (int idx = tid; idx < 64 * 16; idx += 256) {
    ((float4*)wo1)[idx] = ((const float4*)Wo1)[idx];
    ((float4*)wo2)[idx] = ((const float4*)Wo2)[idx];
  }
  for (int idx = tid; idx < NPB * 64; idx += 256) {
    int n = n0 + (idx >> 6);
    s_row[idx] = (n < NN) ? hv[(size_t)n * 64 + (idx & 63)] : 0.f;
  }
  __syncthreads();

  int c = tid & 63, g = tid >> 6;
  // phase 1: o1 = relu(h@Wo1 + bo1)
  #pragma unroll
  for (int q = 0; q < 8; ++q) {
    int nl = g + 4 * q;
    float a = bo1[c];
    for (int i = 0; i < 64; ++i) a = fmaf(s_row[nl * 64 + i], wo1[i * 64 + c], a);
    s_o1[nl * 64 + c] = fmaxf(a, 0.f);
  }
  __syncthreads();
  // phase 2: o = o1@Wo2 + bo2; norm over [o, x]; write feat
  #pragma unroll
  for (int q = 0; q < 8; ++q) {
    int nl = g + 4 * q;              // all 64 lanes of this wave share node nl
    int n = n0 + nl;
    float b = bo2[c];
    for (int i = 0; i < 64; ++i) b = fmaf(s_o1[nl * 64 + i], wo2[i * 64 + c], b);
    float xv = (c < NATOM && n < NN) ? x[(size_t)n * NATOM + c] : 0.f;
    float sq = b * b + xv * xv;
    #pragma unroll
    for (int off = 1; off < 64; off <<= 1) sq += __shfl_xor(sq, off);
    if (n >= NN) continue;
    float inv = 1.f / fmaxf(sqrtf(sq), 1e-12f);
    feat[(size_t)n * 90 + c] = b * inv;
    if (c < NATOM) feat[(size_t)n * 90 + 64 + c] = xv * inv;
  }
}

// ---------------- readout: segment mean prep via binary search (no atomics)
static __device__ __forceinline__ int lbound(const int* __restrict__ b, int v) {
  int lo = 0, hi = NN;
  while (lo < hi) { int m = (lo + hi) >> 1; if (b[m] < v) lo = m + 1; else hi = m; }
  return lo;
}

__global__ __launch_bounds__(128) void readout_kernel(
    const float* __restrict__ feat, const int* __restrict__ batch,
    float* __restrict__ readout, float* __restrict__ cnt) {
  __shared__ int bounds[2];
  int g = blockIdx.x;                // 0..63
  int t = threadIdx.x;
  if (t == 0) bounds[0] = lbound(batch, g);
  if (t == 1) bounds[1] = lbound(batch, g + 1);
  __syncthreads();
  int lo = bounds[0], hi = bounds[1];
  if (t < 90) {
    float a0 = 0.f, a1 = 0.f, a2 = 0.f, a3 = 0.f;
    int n = lo;
    for (; n + 3 < hi; n += 4) {
      a0 += feat[(size_t)n * 90 + t];
      a1 += feat[(size_t)(n + 1) * 90 + t];
      a2 += feat[(size_t)(n + 2) * 90 + t];
      a3 += feat[(size_t)(n + 3) * 90 + t];
    }
    for (; n < hi; ++n) a0 += feat[(size_t)n * 90 + t];
    readout[g * 90 + t] = (a0 + a1) + (a2 + a3);
  }
  if (t == 0) cnt[g] = (float)(hi - lo);
}

__global__ __launch_bounds__(64) void ratio_kernel(
    const float* __restrict__ readout, const float* __restrict__ cnt,
    const float* __restrict__ Wp, const float* __restrict__ bp,
    float* __restrict__ ratio) {
  int g = threadIdx.x;
  float c = fmaxf(cnt[g], 1.f);
  float a = bp[0];
  for (int j = 0; j < 90; ++j) a = fmaf(readout[g * 90 + j] / c, Wp[j], a);
  ratio[g] = 1.f / (1.f + __expf(-a));
}

// ==================== launcher ====================

extern "C" void kernel_launch(void* const* d_in, const int* in_sizes, int n_in,
                              void* d_out, int out_size, void* d_ws, size_t ws_size,
                              hipStream_t stream) {
  const float* x      = (const float*)d_in[0];
  const int*   ei     = (const int*)  d_in[1];
  const float* ea     = (const float*)d_in[2];
  const int*   batch  = (const int*)  d_in[3];
  const float* W_in   = (const float*)d_in[4];
  const float* b_in   = (const float*)d_in[5];
  const float* We1    = (const float*)d_in[6];
  const float* be1    = (const float*)d_in[7];
  const float* We2    = (const float*)d_in[8];
  const float* be2    = (const float*)d_in[9];
  const float* W_root = (const float*)d_in[10];
  const float* b_conv = (const float*)d_in[11];
  const float* W_ih   = (const float*)d_in[12];
  const float* b_ih   = (const float*)d_in[13];
  const float* W_hh   = (const float*)d_in[14];
  const float* b_hh   = (const float*)d_in[15];
  const float* Wo1    = (const float*)d_in[16];
  const float* bo1    = (const float*)d_in[17];
  const float* Wo2    = (const float*)d_in[18];
  const float* bo2    = (const float*)d_in[19];
  const float* Wp     = (const float*)d_in[20];
  const float* bp     = (const float*)d_in[21];

  const int* srcp = ei;
  const int* dstp = ei + NE;
  float* feat  = (float*)d_out;
  float* ratio = feat + (size_t)NN * 90;

  // ws layout (bytes): total ~27.2 MB (round-1 proved >= 39.3 MB available)
  char* wsb = (char*)d_ws;
  ushort* Upkt   = (ushort*)(wsb + 0);            // 33*50176*4*2  = 13,246,464
  ushort* Bpk    = (ushort*)(wsb + 13246464);     // 33*8*4*64*8*2 =  1,081,344
  float*  h      = (float*) (wsb + 14327808);     // 6,400,000
  float*  agg    = (float*) (wsb + 20727808);     // 6,400,000
  float*  readout= (float*) (wsb + 27127808);     // 23,040
  float*  cnt    = (float*) (wsb + 27150848);     // 256

  edge_mlp_pack_kernel<<<NEP2 / 64, 256, 0, stream>>>(ea, We1, be1, Upkt);
  bpk_pack_kernel<<<(NCH * 8 * 4 * 64) / 256, 256, 0, stream>>>(We2, be2, Bpk);
  node_in_kernel<<<(NN * 64 + 255) / 256, 256, 0, stream>>>(x, W_in, b_in, h);

  for (int it = 0; it < NUM_ITER; ++it) {
    hipMemsetAsync(agg, 0, (size_t)NN * 64 * sizeof(float), stream);
    edge_rgemm_kernel<<<NBLK, 512, 0, stream>>>(Upkt, Bpk, h, srcp, dstp, agg);
    node_update_kernel<<<(NN + NPB - 1) / NPB, 256, 0, stream>>>(
        h, agg, W_root, b_conv, W_ih, b_ih, W_hh, b_hh);
  }

  head2_kernel<<<(NN + NPB - 1) / NPB, 256, 0, stream>>>(
      h, x, Wo1, bo1, Wo2, bo2, feat);
  readout_kernel<<<64, 128, 0, stream>>>(feat, batch, readout, cnt);
  ratio_kernel<<<1, 64, 0, stream>>>(readout, cnt, Wp, bp, ratio);
}

// Round 7
// 423.886 us; speedup vs baseline: 9.7545x; 1.6589x over previous
//
#include <hip/hip_runtime.h>
#include <math.h>

#define NN 25000
#define NE 50000
#define NEP2 50176            // 196 * 256 edges (padded)
#define NBLK 196
#define NATOM 26
#define NUM_ITER 3
#define NCH 33                // K' = 33 chunks x 256 (4 k-values x 64 i's)
#define NPB 32

typedef __attribute__((ext_vector_type(8))) short bf16x8;
typedef __attribute__((ext_vector_type(8))) unsigned short ushort8_t;
typedef __attribute__((ext_vector_type(4))) float f32x4;
union FragU { bf16x8 v; ushort4 q[2]; };

static __device__ __forceinline__ ushort f2bf(float f) {
  unsigned u = __float_as_uint(f);
  unsigned r = (u + 0x7FFFu + ((u >> 16) & 1u)) >> 16;
  return (ushort)r;
}
static __device__ __forceinline__ unsigned cvt_pk_bf16(float a, float b) {
  unsigned r;
  asm("v_cvt_pk_bf16_f32 %0, %1, %2" : "=v"(r) : "v"(a), "v"(b));
  return r;
}
static __device__ __forceinline__ float bflo(unsigned u) { return __uint_as_float(u << 16); }
static __device__ __forceinline__ float bfhi(unsigned u) { return __uint_as_float(u & 0xFFFF0000u); }

// ---------------- U pack: relu(ea@We1+be1) -> Upkt[g][e][4] bf16 (k-group-major)
__global__ __launch_bounds__(256) void edge_mlp_pack_kernel(
    const float* __restrict__ ea, const float* __restrict__ We1,
    const float* __restrict__ be1, ushort* __restrict__ Upkt) {
  int t = threadIdx.x;
  int el = t & 63, seg = t >> 6;
  int e = blockIdx.x * 64 + el;       // grid 784 -> e < 50176
  bool valid = (e < NE);
  float a0 = 0.f, a1 = 0.f, a2 = 0.f, a3 = 0.f;
  if (valid) { a0 = ea[e * 4]; a1 = ea[e * 4 + 1]; a2 = ea[e * 4 + 2]; a3 = ea[e * 4 + 3]; }
  #pragma unroll
  for (int q = 0; q < 8; ++q) {
    int g = seg * 8 + q;              // k-group 0..31 (k = 4g..4g+3 < 128)
    ushort out[4];
    #pragma unroll
    for (int kk = 0; kk < 4; ++kk) {
      int k = g * 4 + kk;
      float v = be1[k];
      v = fmaf(a0, We1[k], v);
      v = fmaf(a1, We1[128 + k], v);
      v = fmaf(a2, We1[256 + k], v);
      v = fmaf(a3, We1[384 + k], v);
      out[kk] = valid ? f2bf(fmaxf(v, 0.f)) : (ushort)0;
    }
    *(ushort4*)&Upkt[((size_t)g * NEP2 + e) * 4] = *(ushort4*)out;
  }
  if (seg == 0) {                     // g=32: k=128 -> 1.0 (be2 fold), 129..131 -> 0
    ushort out[4] = {(ushort)(valid ? 0x3F80 : 0), 0, 0, 0};
    *(ushort4*)&Upkt[((size_t)32 * NEP2 + e) * 4] = *(ushort4*)out;
  }
}

// ---------------- B pack: We2ext[f][o] -> per-lane fragment order
__global__ __launch_bounds__(256) void bpk_pack_kernel(
    const float* __restrict__ We2, const float* __restrict__ be2,
    ushort* __restrict__ Bpk) {
  int idx = blockIdx.x * 256 + threadIdx.x;   // 264 blocks -> 67584 = 33*8*4*64
  int lane = idx & 63;
  int nt = (idx >> 6) & 3;
  int ks = (idx >> 8) & 7;
  int c = idx >> 11;
  int l15 = lane & 15, lg = lane >> 4;
  int o = nt * 16 + l15;
  ushort v[8];
  #pragma unroll
  for (int j = 0; j < 8; ++j) {
    int kl = (j < 4) ? (4 * lg + j) : (12 + 4 * lg + j);   // split-halves k-map
    int f = c * 256 + ks * 32 + kl;
    int k = f >> 6, i = f & 63;
    float wv = 0.f;
    if (k < 128) wv = We2[(size_t)k * 4096 + i * 64 + o];
    else if (k == 128) wv = be2[i * 64 + o];
    v[j] = f2bf(wv);
  }
  *(ushort8_t*)(Bpk + (size_t)idx * 8) = *(ushort8_t*)v;
}

// ---------------- GRU/conv weight pack: fragment-linear bf16 in ws
// Wr_pk  [ (ks*4+nt)*64+lane ][8]  : B[i][c]   = W_root[i*64+c]          (2ks x 4nt)
// Bih_pk [ (ks*12+nt)*64+lane][8]  : B[i][jo]  = W_ih[jo*64+i]           (2ks x 12nt)
// Bhh_pk [ (ks*12+nt)*64+lane][8]  : B[i][jo]  = W_hh[jo*64+i]
__global__ __launch_bounds__(256) void nw_pack_kernel(
    const float* __restrict__ W_root, const float* __restrict__ W_ih,
    const float* __restrict__ W_hh, ushort* __restrict__ Wr_pk,
    ushort* __restrict__ Bih_pk, ushort* __restrict__ Bhh_pk) {
  int idx = blockIdx.x * 256 + threadIdx.x;   // 14 blocks -> 3584 frags
  if (idx >= 3584) return;
  int lane, nt, ks, kind;
  ushort* dstp;
  if (idx < 512)      { kind = 0; int f = idx;        lane = f & 63; nt = (f >> 6) % 4;  ks = (f >> 6) / 4;  dstp = Wr_pk  + (size_t)f * 8; }
  else if (idx < 2048){ kind = 1; int f = idx - 512;  lane = f & 63; nt = (f >> 6) % 12; ks = (f >> 6) / 12; dstp = Bih_pk + (size_t)f * 8; }
  else                { kind = 2; int f = idx - 2048; lane = f & 63; nt = (f >> 6) % 12; ks = (f >> 6) / 12; dstp = Bhh_pk + (size_t)f * 8; }
  int l15 = lane & 15, lg = lane >> 4;
  int col = nt * 16 + l15;
  ushort v[8];
  #pragma unroll
  for (int j = 0; j < 8; ++j) {
    int kl = (j < 4) ? (4 * lg + j) : (12 + 4 * lg + j);
    int i = ks * 32 + kl;
    float wv;
    if (kind == 0)      wv = W_root[i * 64 + col];
    else if (kind == 1) wv = W_ih[col * 64 + i];
    else                wv = W_hh[col * 64 + i];
    v[j] = f2bf(wv);
  }
  *(ushort8_t*)dstp = *(ushort8_t*)v;
}

// ---------------- fused edge-message GEMM: msg = (U (x) s) @ We2flat, + scatter
__global__ __launch_bounds__(512, 1) void edge_rgemm_kernel(
    const ushort* __restrict__ Upkt, const ushort* __restrict__ Bpk,
    const float* __restrict__ hv, const int* __restrict__ src,
    const int* __restrict__ dst, float* __restrict__ agg) {
  __shared__ ushort sB[2][16384];   // 2 x 32KB frag-packed B chunk (2048 frags x 8)
  __shared__ ushort sU[2][1024];    // 2 x 2KB U chunk [256 e][4 k]
  __shared__ ushort sS[256][72];    // s bf16, padded row
  int tid = threadIdx.x;            // 0..511
  int lane = tid & 63, w = tid >> 6;
  int l15 = lane & 15, lg = lane >> 4;
  int e0 = blockIdx.x * 256;

  #pragma unroll
  for (int r = 0; r < 8; ++r) {
    int idx = r * 512 + tid;
    int el = idx >> 4, part = idx & 15;
    int e = e0 + el;
    float4 v = make_float4(0.f, 0.f, 0.f, 0.f);
    if (e < NE) v = ((const float4*)hv)[(size_t)src[e] * 16 + part];
    unsigned lo = cvt_pk_bf16(v.x, v.y);
    unsigned hi = cvt_pk_bf16(v.z, v.w);
    *(uint2*)&sS[el][part * 4] = make_uint2(lo, hi);
  }

  ushort8_t rB[4]; uint2 rU;
  #pragma unroll
  for (int r = 0; r < 4; ++r)
    rB[r] = *(const ushort8_t*)(Bpk + ((size_t)r * 512 + tid) * 8);
  if (tid < 256) rU = *(const uint2*)(Upkt + (size_t)e0 * 4 + tid * 4);
  #pragma unroll
  for (int r = 0; r < 4; ++r)
    *(ushort8_t*)&sB[0][((size_t)r * 512 + tid) * 8] = rB[r];
  if (tid < 256) *(uint2*)&sU[0][tid * 4] = rU;
  __syncthreads();

  float4 sreg[2][2][2];
  #pragma unroll
  for (int mt = 0; mt < 2; ++mt)
    #pragma unroll
    for (int p = 0; p < 2; ++p)
      #pragma unroll
      for (int g = 0; g < 2; ++g) {
        uint2 d = *(const uint2*)&sS[w * 32 + mt * 16 + l15][p * 32 + g * 16 + 4 * lg];
        sreg[mt][p][g] = make_float4(bflo(d.x), bfhi(d.x), bflo(d.y), bfhi(d.y));
      }

  f32x4 acc[2][4];
  #pragma unroll
  for (int mt = 0; mt < 2; ++mt)
    #pragma unroll
    for (int nt = 0; nt < 4; ++nt) acc[mt][nt] = (f32x4){0.f, 0.f, 0.f, 0.f};

  for (int c = 0; c < NCH; ++c) {
    int cur = c & 1;
    bool more = (c + 1 < NCH);
    if (more) {
      const ushort* bs = Bpk + (size_t)(c + 1) * 16384;
      #pragma unroll
      for (int r = 0; r < 4; ++r)
        rB[r] = *(const ushort8_t*)(bs + ((size_t)r * 512 + tid) * 8);
      if (tid < 256)
        rU = *(const uint2*)(Upkt + ((size_t)(c + 1) * NEP2 + e0) * 4 + tid * 4);
    }
    float uu[2][4];
    #pragma unroll
    for (int mt = 0; mt < 2; ++mt) {
      uint2 d = *(const uint2*)&sU[cur][(w * 32 + mt * 16 + l15) * 4];
      uu[mt][0] = bflo(d.x); uu[mt][1] = bfhi(d.x);
      uu[mt][2] = bflo(d.y); uu[mt][3] = bfhi(d.y);
    }
    #pragma unroll
    for (int ks = 0; ks < 8; ++ks) {
      int p = ks & 1, ku = ks >> 1;
      bf16x8 bfr[4];
      #pragma unroll
      for (int nt = 0; nt < 4; ++nt)
        bfr[nt] = *(const bf16x8*)&sB[cur][(((size_t)ks * 4 + nt) * 64 + lane) * 8];
      #pragma unroll
      for (int mt = 0; mt < 2; ++mt) {
        float u = uu[mt][ku];
        float4 s0 = sreg[mt][p][0], s1 = sreg[mt][p][1];
        union { bf16x8 v; unsigned u32[4]; } af;
        af.u32[0] = cvt_pk_bf16(s0.x * u, s0.y * u);
        af.u32[1] = cvt_pk_bf16(s0.z * u, s0.w * u);
        af.u32[2] = cvt_pk_bf16(s1.x * u, s1.y * u);
        af.u32[3] = cvt_pk_bf16(s1.z * u, s1.w * u);
        #pragma unroll
        for (int nt = 0; nt < 4; ++nt)
          acc[mt][nt] = __builtin_amdgcn_mfma_f32_16x16x32_bf16(af.v, bfr[nt], acc[mt][nt], 0, 0, 0);
      }
    }
    if (more) {
      int nb = cur ^ 1;
      #pragma unroll
      for (int r = 0; r < 4; ++r)
        *(ushort8_t*)&sB[nb][((size_t)r * 512 + tid) * 8] = rB[r];
      if (tid < 256) *(uint2*)&sU[nb][tid * 4] = rU;
    }
    __syncthreads();
  }

  #pragma unroll
  for (int mt = 0; mt < 2; ++mt) {
    #pragma unroll
    for (int rr = 0; rr < 4; ++rr) {
      int e = e0 + w * 32 + mt * 16 + lg * 4 + rr;
      if (e < NE) {
        int d = dst[e];
        #pragma unroll
        for (int nt = 0; nt < 4; ++nt)
          atomicAdd(&agg[(size_t)d * 64 + nt * 16 + l15], acc[mt][nt][rr]);
      }
    }
  }
}

// ---------------- node input transform
__global__ __launch_bounds__(256) void node_in_kernel(
    const float* __restrict__ x, const float* __restrict__ W_in,
    const float* __restrict__ b_in, float* __restrict__ h) {
  int idx = blockIdx.x * 256 + threadIdx.x;
  if (idx >= NN * 64) return;
  int n = idx >> 6, c = idx & 63;
  float acc = b_in[c];
  #pragma unroll
  for (int j = 0; j < NATOM; ++j) acc = fmaf(x[n * NATOM + j], W_in[j * 64 + c], acc);
  h[idx] = fmaxf(acc, 0.f);
}

// ---------------- node update v2: MFMA GRU. 128 nodes/block, 256 thr (4 waves x 32 nodes)
__global__ __launch_bounds__(256, 1) void node_update2_kernel(
    float* __restrict__ hv, const float* __restrict__ agg,
    const ushort* __restrict__ Wr_pk, const ushort* __restrict__ Bih_pk,
    const ushort* __restrict__ Bhh_pk, const float* __restrict__ b_conv,
    const float* __restrict__ b_ih, const float* __restrict__ b_hh) {
  __shared__ ushort h_lds[128][72];   // 18 KB
  __shared__ ushort m_lds[128][72];   // 18 KB
  int tid = threadIdx.x;
  int lane = tid & 63, w = tid >> 6;
  int l15 = lane & 15, lg = lane >> 4;
  int n0 = blockIdx.x * 128;

  // stage h (bf16)
  #pragma unroll
  for (int r = 0; r < 8; ++r) {
    int idx = r * 256 + tid;          // 2048 = 128 rows x 16 float4-parts
    int row = idx >> 4, part = idx & 15;
    int n = n0 + row;
    float4 v = make_float4(0.f, 0.f, 0.f, 0.f);
    if (n < NN) v = ((const float4*)hv)[(size_t)n * 16 + part];
    *(uint2*)&h_lds[row][part * 4] =
        make_uint2(cvt_pk_bf16(v.x, v.y), cvt_pk_bf16(v.z, v.w));
  }
  __syncthreads();

  // A-frags of h (same mapping as edge_rgemm's sreg: i = ks*32 + kl(lg,j))
  bf16x8 ah[2][2];
  #pragma unroll
  for (int mt = 0; mt < 2; ++mt)
    #pragma unroll
    for (int ks = 0; ks < 2; ++ks) {
      int row = w * 32 + mt * 16 + l15;
      FragU f;
      f.q[0] = *(const ushort4*)&h_lds[row][ks * 32 + 4 * lg];
      f.q[1] = *(const ushort4*)&h_lds[row][ks * 32 + 16 + 4 * lg];
      ah[mt][ks] = f.v;
    }

  // stage 1: m = relu(h@Wroot + agg + b_conv)
  f32x4 accm[2][4];
  #pragma unroll
  for (int mt = 0; mt < 2; ++mt)
    #pragma unroll
    for (int nt = 0; nt < 4; ++nt) accm[mt][nt] = (f32x4){0.f, 0.f, 0.f, 0.f};
  #pragma unroll
  for (int ks = 0; ks < 2; ++ks)
    #pragma unroll
    for (int nt = 0; nt < 4; ++nt) {
      bf16x8 b = *(const bf16x8*)(Wr_pk + ((size_t)((ks * 4 + nt) * 64 + lane)) * 8);
      #pragma unroll
      for (int mt = 0; mt < 2; ++mt)
        accm[mt][nt] = __builtin_amdgcn_mfma_f32_16x16x32_bf16(ah[mt][ks], b, accm[mt][nt], 0, 0, 0);
    }
  #pragma unroll
  for (int mt = 0; mt < 2; ++mt)
    #pragma unroll
    for (int nt = 0; nt < 4; ++nt) {
      int col = nt * 16 + l15;
      float bc = b_conv[col];
      #pragma unroll
      for (int rr = 0; rr < 4; ++rr) {
        int row = w * 32 + mt * 16 + lg * 4 + rr;
        int n = n0 + row;
        float val = 0.f;
        if (n < NN) val = fmaxf(accm[mt][nt][rr] + agg[(size_t)n * 64 + col] + bc, 0.f);
        m_lds[row][col] = f2bf(val);
      }
    }
  __syncthreads();

  // A-frags of m
  bf16x8 am[2][2];
  #pragma unroll
  for (int mt = 0; mt < 2; ++mt)
    #pragma unroll
    for (int ks = 0; ks < 2; ++ks) {
      int row = w * 32 + mt * 16 + l15;
      FragU f;
      f.q[0] = *(const ushort4*)&m_lds[row][ks * 32 + 4 * lg];
      f.q[1] = *(const ushort4*)&m_lds[row][ks * 32 + 16 + 4 * lg];
      am[mt][ks] = f.v;
    }

  // stage 2: acc_s = (m@WihT + h@WhhT) for r,z planes; i_n and h_n separate
  f32x4 acc_s[2][8], acc_in[2][4], acc_hn[2][4];
  #pragma unroll
  for (int mt = 0; mt < 2; ++mt) {
    #pragma unroll
    for (int nt = 0; nt < 8; ++nt) acc_s[mt][nt] = (f32x4){0.f, 0.f, 0.f, 0.f};
    #pragma unroll
    for (int nt = 0; nt < 4; ++nt) {
      acc_in[mt][nt] = (f32x4){0.f, 0.f, 0.f, 0.f};
      acc_hn[mt][nt] = (f32x4){0.f, 0.f, 0.f, 0.f};
    }
  }
  #pragma unroll
  for (int ks = 0; ks < 2; ++ks) {
    #pragma unroll
    for (int nt = 0; nt < 8; ++nt) {
      bf16x8 bi = *(const bf16x8*)(Bih_pk + ((size_t)((ks * 12 + nt) * 64 + lane)) * 8);
      bf16x8 bh = *(const bf16x8*)(Bhh_pk + ((size_t)((ks * 12 + nt) * 64 + lane)) * 8);
      #pragma unroll
      for (int mt = 0; mt < 2; ++mt) {
        acc_s[mt][nt] = __builtin_amdgcn_mfma_f32_16x16x32_bf16(am[mt][ks], bi, acc_s[mt][nt], 0, 0, 0);
        acc_s[mt][nt] = __builtin_amdgcn_mfma_f32_16x16x32_bf16(ah[mt][ks], bh, acc_s[mt][nt], 0, 0, 0);
      }
    }
    #pragma unroll
    for (int nt = 8; nt < 12; ++nt) {
      bf16x8 bi = *(const bf16x8*)(Bih_pk + ((size_t)((ks * 12 + nt) * 64 + lane)) * 8);
      bf16x8 bh = *(const bf16x8*)(Bhh_pk + ((size_t)((ks * 12 + nt) * 64 + lane)) * 8);
      #pragma unroll
      for (int mt = 0; mt < 2; ++mt) {
        acc_in[mt][nt - 8] = __builtin_amdgcn_mfma_f32_16x16x32_bf16(am[mt][ks], bi, acc_in[mt][nt - 8], 0, 0, 0);
        acc_hn[mt][nt - 8] = __builtin_amdgcn_mfma_f32_16x16x32_bf16(ah[mt][ks], bh, acc_hn[mt][nt - 8], 0, 0, 0);
      }
    }
  }

  // GRU elementwise; h' = (1-z)*n + z*h_prev (h_prev f32 from global)
  #pragma unroll
  for (int mt = 0; mt < 2; ++mt)
    #pragma unroll
    for (int nt = 0; nt < 4; ++nt) {
      int col = nt * 16 + l15;
      float b_sr = b_ih[col] + b_hh[col];
      float b_sz = b_ih[64 + col] + b_hh[64 + col];
      float b_in_ = b_ih[128 + col];
      float b_hn = b_hh[128 + col];
      #pragma unroll
      for (int rr = 0; rr < 4; ++rr) {
        int row = w * 32 + mt * 16 + lg * 4 + rr;
        int n = n0 + row;
        if (n >= NN) continue;
        float Sr = acc_s[mt][nt][rr] + b_sr;
        float Sz = acc_s[mt][nt + 4][rr] + b_sz;
        float vin = acc_in[mt][nt][rr] + b_in_;
        float vhn = acc_hn[mt][nt][rr] + b_hn;
        float r = 1.f / (1.f + __expf(-Sr));
        float z = 1.f / (1.f + __expf(-Sz));
        float nn = tanhf(fmaf(r, vhn, vin));
        float hp = hv[(size_t)n * 64 + col];
        hv[(size_t)n * 64 + col] = (1.f - z) * nn + z * hp;
      }
    }
}

// ---------------- head v3: feat only (NO atomics)
__global__ __launch_bounds__(256) void head2_kernel(
    const float* __restrict__ hv, const float* __restrict__ x,
    const float* __restrict__ Wo1, const float* __restrict__ bo1,
    const float* __restrict__ Wo2, const float* __restrict__ bo2,
    float* __restrict__ feat) {
  __shared__ float wo1[64 * 64];
  __shared__ float wo2[64 * 64];
  __shared__ float s_row[NPB * 64];
  __shared__ float s_o1[NPB * 64];
  int tid = threadIdx.x;
  int n0 = blockIdx.x * NPB;

  for (int idx = tid; idx < 64 * 16; idx += 256) {
    ((float4*)wo1)[idx] = ((const float4*)Wo1)[idx];
    ((float4*)wo2)[idx] = ((const float4*)Wo2)[idx];
  }
  for (int idx = tid; idx < NPB * 64; idx += 256) {
    int n = n0 + (idx >> 6);
    s_row[idx] = (n < NN) ? hv[(size_t)n * 64 + (idx & 63)] : 0.f;
  }
  __syncthreads();

  int c = tid & 63, g = tid >> 6;
  #pragma unroll
  for (int q = 0; q < 8; ++q) {
    int nl = g + 4 * q;
    float a = bo1[c];
    for (int i = 0; i < 64; ++i) a = fmaf(s_row[nl * 64 + i], wo1[i * 64 + c], a);
    s_o1[nl * 64 + c] = fmaxf(a, 0.f);
  }
  __syncthreads();
  #pragma unroll
  for (int q = 0; q < 8; ++q) {
    int nl = g + 4 * q;
    int n = n0 + nl;
    float b = bo2[c];
    for (int i = 0; i < 64; ++i) b = fmaf(s_o1[nl * 64 + i], wo2[i * 64 + c], b);
    float xv = (c < NATOM && n < NN) ? x[(size_t)n * NATOM + c] : 0.f;
    float sq = b * b + xv * xv;
    #pragma unroll
    for (int off = 1; off < 64; off <<= 1) sq += __shfl_xor(sq, off);
    if (n >= NN) continue;
    float inv = 1.f / fmaxf(sqrtf(sq), 1e-12f);
    feat[(size_t)n * 90 + c] = b * inv;
    if (c < NATOM) feat[(size_t)n * 90 + 64 + c] = xv * inv;
  }
}

// ---------------- readout: segment mean prep via binary search (no atomics)
static __device__ __forceinline__ int lbound(const int* __restrict__ b, int v) {
  int lo = 0, hi = NN;
  while (lo < hi) { int m = (lo + hi) >> 1; if (b[m] < v) lo = m + 1; else hi = m; }
  return lo;
}

__global__ __launch_bounds__(128) void readout_kernel(
    const float* __restrict__ feat, const int* __restrict__ batch,
    float* __restrict__ readout, float* __restrict__ cnt) {
  __shared__ int bounds[2];
  int g = blockIdx.x;                // 0..63
  int t = threadIdx.x;
  if (t == 0) bounds[0] = lbound(batch, g);
  if (t == 1) bounds[1] = lbound(batch, g + 1);
  __syncthreads();
  int lo = bounds[0], hi = bounds[1];
  if (t < 90) {
    float a0 = 0.f, a1 = 0.f, a2 = 0.f, a3 = 0.f;
    int n = lo;
    for (; n + 3 < hi; n += 4) {
      a0 += feat[(size_t)n * 90 + t];
      a1 += feat[(size_t)(n + 1) * 90 + t];
      a2 += feat[(size_t)(n + 2) * 90 + t];
      a3 += feat[(size_t)(n + 3) * 90 + t];
    }
    for (; n < hi; ++n) a0 += feat[(size_t)n * 90 + t];
    readout[g * 90 + t] = (a0 + a1) + (a2 + a3);
  }
  if (t == 0) cnt[g] = (float)(hi - lo);
}

__global__ __launch_bounds__(64) void ratio_kernel(
    const float* __restrict__ readout, const float* __restrict__ cnt,
    const float* __restrict__ Wp, const float* __restrict__ bp,
    float* __restrict__ ratio) {
  int g = threadIdx.x;
  float c = fmaxf(cnt[g], 1.f);
  float a = bp[0];
  for (int j = 0; j < 90; ++j) a = fmaf(readout[g * 90 + j] / c, Wp[j], a);
  ratio[g] = 1.f / (1.f + __expf(-a));
}

// ==================== launcher ====================

extern "C" void kernel_launch(void* const* d_in, const int* in_sizes, int n_in,
                              void* d_out, int out_size, void* d_ws, size_t ws_size,
                              hipStream_t stream) {
  const float* x      = (const float*)d_in[0];
  const int*   ei     = (const int*)  d_in[1];
  const float* ea     = (const float*)d_in[2];
  const int*   batch  = (const int*)  d_in[3];
  const float* W_in   = (const float*)d_in[4];
  const float* b_in   = (const float*)d_in[5];
  const float* We1    = (const float*)d_in[6];
  const float* be1    = (const float*)d_in[7];
  const float* We2    = (const float*)d_in[8];
  const float* be2    = (const float*)d_in[9];
  const float* W_root = (const float*)d_in[10];
  const float* b_conv = (const float*)d_in[11];
  const float* W_ih   = (const float*)d_in[12];
  const float* b_ih   = (const float*)d_in[13];
  const float* W_hh   = (const float*)d_in[14];
  const float* b_hh   = (const float*)d_in[15];
  const float* Wo1    = (const float*)d_in[16];
  const float* bo1    = (const float*)d_in[17];
  const float* Wo2    = (const float*)d_in[18];
  const float* bo2    = (const float*)d_in[19];
  const float* Wp     = (const float*)d_in[20];
  const float* bp     = (const float*)d_in[21];

  const int* srcp = ei;
  const int* dstp = ei + NE;
  float* feat  = (float*)d_out;
  float* ratio = feat + (size_t)NN * 90;

  // ws layout (bytes): total ~27.2 MB (round-1 proved >= 39.3 MB available)
  char* wsb = (char*)d_ws;
  ushort* Upkt   = (ushort*)(wsb + 0);            // 13,246,464
  ushort* Bpk    = (ushort*)(wsb + 13246464);     //  1,081,344
  float*  h      = (float*) (wsb + 14327808);     //  6,400,000
  float*  agg    = (float*) (wsb + 20727808);     //  6,400,000
  float*  readout= (float*) (wsb + 27127808);     //     23,040
  float*  cnt    = (float*) (wsb + 27150848);     //        256
  ushort* Wr_pk  = (ushort*)(wsb + 27151104);     //      8,192
  ushort* Bih_pk = (ushort*)(wsb + 27159296);     //     24,576
  ushort* Bhh_pk = (ushort*)(wsb + 27183872);     //     24,576  -> 27,208,448 total

  edge_mlp_pack_kernel<<<NEP2 / 64, 256, 0, stream>>>(ea, We1, be1, Upkt);
  bpk_pack_kernel<<<(NCH * 8 * 4 * 64) / 256, 256, 0, stream>>>(We2, be2, Bpk);
  nw_pack_kernel<<<14, 256, 0, stream>>>(W_root, W_ih, W_hh, Wr_pk, Bih_pk, Bhh_pk);
  node_in_kernel<<<(NN * 64 + 255) / 256, 256, 0, stream>>>(x, W_in, b_in, h);

  for (int it = 0; it < NUM_ITER; ++it) {
    hipMemsetAsync(agg, 0, (size_t)NN * 64 * sizeof(float), stream);
    edge_rgemm_kernel<<<NBLK, 512, 0, stream>>>(Upkt, Bpk, h, srcp, dstp, agg);
    node_update2_kernel<<<(NN + 127) / 128, 256, 0, stream>>>(
        h, agg, Wr_pk, Bih_pk, Bhh_pk, b_conv, b_ih, b_hh);
  }

  head2_kernel<<<(NN + NPB - 1) / NPB, 256, 0, stream>>>(
      h, x, Wo1, bo1, Wo2, bo2, feat);
  readout_kernel<<<64, 128, 0, stream>>>(feat, batch, readout, cnt);
  ratio_kernel<<<1, 64, 0, stream>>>(readout, cnt, Wp, bp, ratio);
}